// Round 4
// baseline (329.664 us; speedup 1.0000x reference)
//
#include <hip/hip_runtime.h>
#include <cstdint>
#include <cstddef>

// ---------------------------------------------------------------------------
// RestrictedTransformerEncoderLayer on MI355X (gfx950)  — ROUND 14
// B=2, L=2048, E=1024, H=16, D=64, FF=4096, WIN=128.
// External I/O f32; intermediates bf16; output f32.
// R14: gemm64 DELETED. Its 64x128 tile (waves own 64x32) costs 0.75
// ds_read_b128 per MFMA -> LDS-pipe floor ~858cy/block-step vs matrix 310cy;
// measured wall ~1005cy/step == LDS-bound, pipelining can't help. The 128^2
// tile (waves own 64x64) costs 0.5 reads/MFMA (-33% LDS reads, -25% stage
// writes per FLOP). OutProj and FF2 now run through gemm128 at grid (8,32)
// = 256 blocks = 1 block/CU; the R13 counted-vmcnt 2-deep pipeline +
// ks-split covers latency within the single resident block.
// gemm128 unchanged from R13 (counted vmcnt(8), ks-split, XCD swizzle,
// setprio) — it improved FF1 in R13.
// Workspace (peak 50.33 MB):
//   srcb/x1b bf16 [0,        8388608)   (LN1 in-place over srcb)
//   qkv  bf16     [8388608,  33554432)  dead after attn
//   ctx  bf16     [33554432, 41943040)  dead after out-proj
//   attnb bf16    [8388608,  16777216)  (reuse qkv)  dead after LN1
//   ff1  bf16     [8388608,  41943040)
//   wslot bf16    [41943040, 50331648)  converted weight (serial reuse)
// ---------------------------------------------------------------------------

typedef __attribute__((ext_vector_type(8))) short short8;   // 8 x bf16 MFMA frag
typedef __attribute__((ext_vector_type(4))) float f32x4;    // MFMA accumulator

__device__ __forceinline__ float b2f(unsigned short u) {
  union { unsigned int i; float f; } x; x.i = ((unsigned int)u) << 16; return x.f;
}
__device__ __forceinline__ unsigned short f2b(float f) {
  union { float f; unsigned int i; } x; x.f = f;
  unsigned int i = x.i;
  unsigned int r = (i + 0x7FFFu + ((i >> 16) & 1u)) >> 16;  // RNE
  return (unsigned short)r;
}
__device__ __forceinline__ uint4 pack8(float4 f0, float4 f1) {
  uint4 r;
  r.x = (unsigned)f2b(f0.x) | ((unsigned)f2b(f0.y) << 16);
  r.y = (unsigned)f2b(f0.z) | ((unsigned)f2b(f0.w) << 16);
  r.z = (unsigned)f2b(f1.x) | ((unsigned)f2b(f1.y) << 16);
  r.w = (unsigned)f2b(f1.z) | ((unsigned)f2b(f1.w) << 16);
  return r;
}

// async global->LDS, 16B/lane; LDS base wave-uniform, lanes write base+lane*16
__device__ __forceinline__ void gl_lds16(const unsigned short* g, unsigned short* l) {
  __builtin_amdgcn_global_load_lds(
      (const __attribute__((address_space(1))) unsigned int*)g,
      (__attribute__((address_space(3))) unsigned int*)l, 16, 0, 0);
}

// ---------------------------------------------------------------------------
// f32 -> bf16 convert
// ---------------------------------------------------------------------------
__global__ __launch_bounds__(256) void conv_k(
    const float* __restrict__ in, unsigned short* __restrict__ out, int n)
{
  const int i = (blockIdx.x * 256 + threadIdx.x) * 8;
  if (i < n) {
    const float4 f0 = *(const float4*)(in + i);
    const float4 f1 = *(const float4*)(in + i + 4);
    *(uint4*)(out + i) = pack8(f0, f1);
  }
}

// ---------------------------------------------------------------------------
// GEMM 128x128 tile, BK=64: out[M,N] = A[M,K] @ W[N,K]^T + bias. bf16 in.
// R13: 2-deep counted-vmcnt pipeline, ks-split MFMA overlap, XCD swizzle.
// Swizzle (8x16B chunks/row, 128B rows): slot s of row r holds chunk
// c=(s+r)&7; reader for chunk c uses slot (c-r)&7 (conflict-free).
// Waves own 64x64 -> 16 ds_read_b128 feed 32 MFMA (0.5 reads/MFMA).
// ---------------------------------------------------------------------------
template<int RELU, int OUT32>
__global__ __launch_bounds__(256) void gemm128(
    const unsigned short* __restrict__ A, const unsigned short* __restrict__ Wb,
    const float* __restrict__ bias, void* __restrict__ out,
    int M, int N, int K)
{
  __shared__ unsigned short As[2][128 * 64];   // 32 KB
  __shared__ unsigned short Bs[2][128 * 64];   // 32 KB

  const int tid = threadIdx.x;
  const int lane = tid & 63, wid = tid >> 6;

  // XCD-aware bijective remap (total blocks % 8 == 0 at all call sites)
  const int nwgx = gridDim.x;
  const int flat = blockIdx.y * nwgx + blockIdx.x;
  const int chunk = (nwgx * gridDim.y) >> 3;
  const int nf = (flat & 7) * chunk + (flat >> 3);
  const int m0 = (nf / nwgx) * 128, n0 = (nf % nwgx) * 128;

  // staging: 1024 slots each; wave w covers slots [w*256, +256) = rows w*32..+31
  const unsigned short* gA[4];
  const unsigned short* gW[4];
  int ldsO[4];
#pragma unroll
  for (int i = 0; i < 4; ++i) {
    const int sl = wid * 256 + i * 64 + lane;
    const int r = sl >> 3, s = sl & 7, c = (s + r) & 7;
    gA[i] = A + (size_t)(m0 + r) * K + c * 8;
    gW[i] = Wb + (size_t)(n0 + r) * K + c * 8;
    ldsO[i] = (wid * 256 + i * 64) * 8;
  }

  const int cl = lane & 15;
  const int kg = lane >> 4;
  const int msub = (wid >> 1) * 64, nsub = (wid & 1) * 64;
  int aoff[4][2], boff[4][2];
#pragma unroll
  for (int t = 0; t < 4; ++t) {
    const int ar = msub + t * 16 + cl;
    const int br = nsub + t * 16 + cl;
#pragma unroll
    for (int ks = 0; ks < 2; ++ks) {
      aoff[t][ks] = ar * 64 + ((ks * 4 + kg - ar) & 7) * 8;
      boff[t][ks] = br * 64 + ((ks * 4 + kg - br) & 7) * 8;
    }
  }

  f32x4 acc[4][4];
#pragma unroll
  for (int i = 0; i < 4; ++i)
#pragma unroll
    for (int j = 0; j < 4; ++j) acc[i][j] = (f32x4){0.f, 0.f, 0.f, 0.f};

  const int steps = K >> 6;

  // prologue: stage tiles 0,1 into buffers 0,1 (8 loads each)
  const int pre = steps < 2 ? steps : 2;
  for (int t = 0; t < pre; ++t) {
#pragma unroll
    for (int i = 0; i < 4; ++i) { gl_lds16(gA[i], &As[t][ldsO[i]]); gA[i] += 64; }
#pragma unroll
    for (int i = 0; i < 4; ++i) { gl_lds16(gW[i], &Bs[t][ldsO[i]]); gW[i] += 64; }
  }

  int cur = 0;
  for (int s = 0; s < steps; ++s) {
    // wait for tile s only; tile s+1's 8 loads stay in flight across barrier
    if (s + 1 < steps) asm volatile("s_waitcnt vmcnt(8)" ::: "memory");
    else               asm volatile("s_waitcnt vmcnt(0)" ::: "memory");
    __builtin_amdgcn_s_barrier();   // all waves' tile-s loads now in LDS

    short8 af[4][2], bf[4][2];
#pragma unroll
    for (int t = 0; t < 4; ++t) {   // ks0 reads first
      af[t][0] = *(const short8*)&As[cur][aoff[t][0]];
      bf[t][0] = *(const short8*)&Bs[cur][boff[t][0]];
    }
#pragma unroll
    for (int t = 0; t < 4; ++t) {   // ks1 reads (complete under MFMA ks0)
      af[t][1] = *(const short8*)&As[cur][aoff[t][1]];
      bf[t][1] = *(const short8*)&Bs[cur][boff[t][1]];
    }

    __builtin_amdgcn_s_setprio(1);
#pragma unroll
    for (int mt = 0; mt < 4; ++mt)
#pragma unroll
      for (int nt = 0; nt < 4; ++nt)
        acc[mt][nt] = __builtin_amdgcn_mfma_f32_16x16x32_bf16(af[mt][0], bf[nt][0], acc[mt][nt], 0, 0, 0);
    __builtin_amdgcn_s_setprio(0);

    asm volatile("s_waitcnt lgkmcnt(0)" ::: "memory");  // all frag reads retired
    __builtin_amdgcn_sched_barrier(0);                  // rule #18 fence
    __builtin_amdgcn_s_barrier();   // everyone done reading buf[cur]

    if (s + 2 < steps) {            // stage tile s+2 into just-freed buffer
#pragma unroll
      for (int i = 0; i < 4; ++i) { gl_lds16(gA[i], &As[cur][ldsO[i]]); gA[i] += 64; }
#pragma unroll
      for (int i = 0; i < 4; ++i) { gl_lds16(gW[i], &Bs[cur][ldsO[i]]); gW[i] += 64; }
    }

    __builtin_amdgcn_s_setprio(1);
#pragma unroll
    for (int mt = 0; mt < 4; ++mt)
#pragma unroll
      for (int nt = 0; nt < 4; ++nt)
        acc[mt][nt] = __builtin_amdgcn_mfma_f32_16x16x32_bf16(af[mt][1], bf[nt][1], acc[mt][nt], 0, 0, 0);
    __builtin_amdgcn_s_setprio(0);

    cur ^= 1;
  }

  // epilogue: C/D mapping col = cl, row = kg*4 + r  [m89-verified]
#pragma unroll
  for (int nt = 0; nt < 4; ++nt) {
    const int col = n0 + nsub + nt * 16 + cl;
    const float bvs = bias[col];
#pragma unroll
    for (int mt = 0; mt < 4; ++mt) {
#pragma unroll
      for (int r = 0; r < 4; ++r) {
        const int grow = m0 + msub + mt * 16 + kg * 4 + r;
        float v = acc[mt][nt][r] + bvs;
        if (RELU) v = fmaxf(v, 0.f);
        if (OUT32) ((float*)out)[(size_t)grow * N + col] = v;
        else       ((unsigned short*)out)[(size_t)grow * N + col] = f2b(v);
      }
    }
  }
}

// ---------------------------------------------------------------------------
// MFMA flash attention (unchanged from passing r6-r9).
// ---------------------------------------------------------------------------
__global__ __launch_bounds__(256) void attn_mfma(
    const unsigned short* __restrict__ qkv, unsigned short* __restrict__ ctx)
{
  __shared__ unsigned short Ks[64 * 72];
  __shared__ unsigned short Vt[64 * 72];
  __shared__ unsigned short Ps[64 * 72];

  const int tid = threadIdx.x;
  const int bid = blockIdx.x;
  const int qt = bid & 31, h = (bid >> 5) & 15, b = bid >> 9;
  const int q0 = qt * 64;
  const int wstart = max(0, q0 - 128);
  const int wend = min(2048, q0 + 64 + 128);
  const int ntile = (wend - wstart + 63) >> 6;
  const size_t rowb = (size_t)b * 2048;

  const int lane = tid & 63, wid = tid >> 6;
  const int cl = lane & 15;
  const int kq = (lane >> 4) * 8;
  const int rowg = lane >> 4;

  short8 aQ[2];
#pragma unroll
  for (int ks = 0; ks < 2; ++ks)
    aQ[ks] = *(const short8*)(qkv + (rowb + q0 + wid * 16 + cl) * 3072 + h * 64 + ks * 32 + kq);

  float m_i[4], l_i[4];
  f32x4 O[4];
#pragma unroll
  for (int r = 0; r < 4; ++r) { m_i[r] = -1.0e30f; l_i[r] = 0.f; }
#pragma unroll
  for (int nt = 0; nt < 4; ++nt) O[nt] = (f32x4){0.f, 0.f, 0.f, 0.f};

  for (int t = 0; t < ntile; ++t) {
    const int jbase = wstart + t * 64;
    __syncthreads();
    for (int idx = tid; idx < 512; idx += 256) {
      const int r = idx >> 3, c = idx & 7;
      const int jg = jbase + r;
      uint4 kv = {0u, 0u, 0u, 0u}, vv = {0u, 0u, 0u, 0u};
      if (jg < wend) {
        const size_t base = (rowb + jg) * 3072 + h * 64 + c * 8;
        kv = *(const uint4*)(qkv + base + 1024);
        vv = *(const uint4*)(qkv + base + 2048);
      }
      *(uint4*)&Ks[r * 72 + c * 8] = kv;
      const unsigned short* vs = (const unsigned short*)&vv;
#pragma unroll
      for (int ii = 0; ii < 8; ++ii) Vt[(c * 8 + ii) * 72 + r] = vs[ii];
    }
    __syncthreads();

    f32x4 S[4];
#pragma unroll
    for (int nt = 0; nt < 4; ++nt) S[nt] = (f32x4){0.f, 0.f, 0.f, 0.f};
#pragma unroll
    for (int nt = 0; nt < 4; ++nt)
#pragma unroll
      for (int ks = 0; ks < 2; ++ks) {
        const short8 bK = *(const short8*)&Ks[(nt * 16 + cl) * 72 + ks * 32 + kq];
        S[nt] = __builtin_amdgcn_mfma_f32_16x16x32_bf16(aQ[ks], bK, S[nt], 0, 0, 0);
      }

    float sc[4][4];
#pragma unroll
    for (int nt = 0; nt < 4; ++nt) {
      const int jg = jbase + nt * 16 + cl;
#pragma unroll
      for (int r = 0; r < 4; ++r) {
        const int i = q0 + wid * 16 + rowg * 4 + r;
        const bool v = (jg < wend) && (jg >= i - 128) && (jg <= i + 128);
        sc[nt][r] = v ? S[nt][r] * 0.125f : -1.0e30f;
      }
    }

    float alpha[4], p[4][4];
#pragma unroll
    for (int r = 0; r < 4; ++r) {
      float tm = fmaxf(fmaxf(sc[0][r], sc[1][r]), fmaxf(sc[2][r], sc[3][r]));
      tm = fmaxf(tm, __shfl_xor(tm, 1, 64));
      tm = fmaxf(tm, __shfl_xor(tm, 2, 64));
      tm = fmaxf(tm, __shfl_xor(tm, 4, 64));
      tm = fmaxf(tm, __shfl_xor(tm, 8, 64));
      const float mn = fmaxf(m_i[r], tm);
      alpha[r] = __expf(m_i[r] - mn);
      m_i[r] = mn;
      float ps = 0.f;
#pragma unroll
      for (int nt = 0; nt < 4; ++nt) { p[nt][r] = __expf(sc[nt][r] - mn); ps += p[nt][r]; }
      ps += __shfl_xor(ps, 1, 64);
      ps += __shfl_xor(ps, 2, 64);
      ps += __shfl_xor(ps, 4, 64);
      ps += __shfl_xor(ps, 8, 64);
      l_i[r] = l_i[r] * alpha[r] + ps;
    }

#pragma unroll
    for (int nt = 0; nt < 4; ++nt)
#pragma unroll
      for (int r = 0; r < 4; ++r)
        Ps[(wid * 16 + rowg * 4 + r) * 72 + nt * 16 + cl] = f2b(p[nt][r]);
    __syncthreads();

#pragma unroll
    for (int nt = 0; nt < 4; ++nt)
#pragma unroll
      for (int r = 0; r < 4; ++r) O[nt][r] *= alpha[r];
    short8 aP[2];
#pragma unroll
    for (int ks = 0; ks < 2; ++ks)
      aP[ks] = *(const short8*)&Ps[(wid * 16 + cl) * 72 + ks * 32 + kq];
#pragma unroll
    for (int nt = 0; nt < 4; ++nt)
#pragma unroll
      for (int ks = 0; ks < 2; ++ks) {
        const short8 bV = *(const short8*)&Vt[(nt * 16 + cl) * 72 + ks * 32 + kq];
        O[nt] = __builtin_amdgcn_mfma_f32_16x16x32_bf16(aP[ks], bV, O[nt], 0, 0, 0);
      }
  }

#pragma unroll
  for (int nt = 0; nt < 4; ++nt) {
    const int d = nt * 16 + cl;
#pragma unroll
    for (int r = 0; r < 4; ++r) {
      const int i = q0 + wid * 16 + rowg * 4 + r;
      ctx[(rowb + i) * 1024 + h * 64 + d] = f2b(O[nt][r] / l_i[r]);
    }
  }
}

// ---------------------------------------------------------------------------
// Residual + LayerNorm (unchanged). In-place safe per-row.
// ---------------------------------------------------------------------------
template<int AF32, int BF32, int OF32>
__global__ __launch_bounds__(256) void ln_k(
    const void* __restrict__ a, const void* __restrict__ b,
    const float* __restrict__ g, const float* __restrict__ be,
    void* __restrict__ o)
{
  __shared__ float rbuf[8];
  const int tid = threadIdx.x;
  const size_t base = (size_t)blockIdx.x * 1024;
  const int lane = tid & 63, wid = tid >> 6;

  float xv[4], s = 0.f, sq = 0.f;
#pragma unroll
  for (int t = 0; t < 4; ++t) {
    const int c = tid + t * 256;
    const float av = AF32 ? ((const float*)a)[base + c]
                          : b2f(((const unsigned short*)a)[base + c]);
    const float bv = BF32 ? ((const float*)b)[base + c]
                          : b2f(((const unsigned short*)b)[base + c]);
    const float x = av + bv;
    xv[t] = x; s += x; sq += x * x;
  }
  for (int o2 = 1; o2 < 64; o2 <<= 1) { s += __shfl_xor(s, o2, 64); sq += __shfl_xor(sq, o2, 64); }
  if (lane == 0) { rbuf[wid] = s; rbuf[wid + 4] = sq; }
  __syncthreads();
  s  = rbuf[0] + rbuf[1] + rbuf[2] + rbuf[3];
  sq = rbuf[4] + rbuf[5] + rbuf[6] + rbuf[7];
  const float mean = s * (1.0f / 1024.f);
  const float var = sq * (1.0f / 1024.f) - mean * mean;
  const float rstd = rsqrtf(var + 1e-5f);
#pragma unroll
  for (int t = 0; t < 4; ++t) {
    const int c = tid + t * 256;
    const float y = (xv[t] - mean) * rstd * g[c] + be[c];
    if (OF32) ((float*)o)[base + c] = y;
    else      ((unsigned short*)o)[base + c] = f2b(y);
  }
}

// ---------------------------------------------------------------------------
extern "C" void kernel_launch(void* const* d_in, const int* in_sizes, int n_in,
                              void* d_out, int out_size, void* d_ws, size_t ws_size,
                              hipStream_t stream)
{
  (void)in_sizes; (void)n_in; (void)out_size; (void)ws_size;
  const float* src   = (const float*)d_in[0];
  const float* w_in  = (const float*)d_in[1];
  const float* b_in  = (const float*)d_in[2];
  const float* w_out = (const float*)d_in[3];
  const float* b_out = (const float*)d_in[4];
  const float* w1    = (const float*)d_in[5];
  const float* b1    = (const float*)d_in[6];
  const float* w2    = (const float*)d_in[7];
  const float* b2    = (const float*)d_in[8];
  const float* g1    = (const float*)d_in[9];
  const float* be1   = (const float*)d_in[10];
  const float* g2    = (const float*)d_in[11];
  const float* be2   = (const float*)d_in[12];

  char* ws = (char*)d_ws;
  unsigned short* srcb  = (unsigned short*)(ws);                 // [0, 8388608)
  unsigned short* x1b   = srcb;                                  // in-place over srcb
  unsigned short* qkv   = (unsigned short*)(ws + 8388608);       // [8388608, 33554432)
  unsigned short* ctx   = (unsigned short*)(ws + 33554432);      // [33554432, 41943040)
  unsigned short* attnb = (unsigned short*)(ws + 8388608);       // reuse qkv head
  unsigned short* ff1   = (unsigned short*)(ws + 8388608);       // [8388608, 41943040)
  unsigned short* wslot = (unsigned short*)(ws + 41943040);      // [41943040, 50331648)
  float*          outf  = (float*)d_out;

  // 0) convert src -> bf16 srcb
  conv_k<<<dim3(2048), 256, 0, stream>>>(src, srcb, 4194304);
  // 1) convert in_proj_w; QKV projection -> bf16 qkv
  conv_k<<<dim3(1536), 256, 0, stream>>>(w_in, wslot, 3145728);
  gemm128<0, 0><<<dim3(24, 32), 256, 0, stream>>>(srcb, wslot, b_in, qkv, 4096, 3072, 1024);
  // 2) banded MFMA flash attention -> bf16 ctx
  attn_mfma<<<dim3(1024), 256, 0, stream>>>(qkv, ctx);
  // 3) convert out_w; output projection (gemm128, grid 256 = 1/CU) -> bf16 attnb
  conv_k<<<dim3(512), 256, 0, stream>>>(w_out, wslot, 1048576);
  gemm128<0, 0><<<dim3(8, 32), 256, 0, stream>>>(ctx, wslot, b_out, attnb, 4096, 1024, 1024);
  // 4) LN1(srcb bf16 + attnb bf16) -> bf16 x1b (in-place over srcb)
  ln_k<0, 0, 0><<<dim3(4096), 256, 0, stream>>>(srcb, attnb, g1, be1, x1b);
  // 5) convert lin1_w; FF1 + ReLU -> bf16 ff1
  conv_k<<<dim3(2048), 256, 0, stream>>>(w1, wslot, 4194304);
  gemm128<1, 0><<<dim3(32, 32), 256, 0, stream>>>(x1b, wslot, b1, ff1, 4096, 4096, 1024);
  // 6) convert lin2_w; FF2 (gemm128, grid 256 = 1/CU) -> f32 into d_out
  conv_k<<<dim3(2048), 256, 0, stream>>>(w2, wslot, 4194304);
  gemm128<0, 1><<<dim3(8, 32), 256, 0, stream>>>(ff1, wslot, b2, outf, 4096, 1024, 4096);
  // 7) LN2(x1b bf16 + d_out f32) -> f32 d_out (in-place, per-row safe)
  ln_k<0, 1, 1><<<dim3(4096), 256, 0, stream>>>(x1b, outf, g2, be2, outf);
}

// Round 5
// 311.959 us; speedup vs baseline: 1.0568x; 1.0568x over previous
//
#include <hip/hip_runtime.h>
#include <cstdint>
#include <cstddef>

// ---------------------------------------------------------------------------
// RestrictedTransformerEncoderLayer on MI355X (gfx950)  — ROUND 15
// B=2, L=2048, E=1024, H=16, D=64, FF=4096, WIN=128.
// External I/O f32; intermediates bf16; output f32.
// R15: every 128^2/2-phase variant (R10-R14) lands at 640-690 TF == the
// documented 128^2+2ph ceiling. New gemm256: 256^2 tile, 8 waves (2Mx4N,
// 2 waves/SIMD intra-block TLP), BK=64, 128KB LDS 2-dbuf, counted vmcnt(8),
// 0.375 ds_read/MFMA. A-frag reads split in halves: MFMA half-1 covers
// half-2 reads; stage of tile s+2 overlaps MFMA half-2. QKV grid (12,16),
// FF1 grid (16,16) = 1 block/CU. gemm64 reverted to R12-exact (its best
// measured form, no ks-split/setprio) for OutProj/FF2 (N=1024 can't fill
// 256 CUs at 256^2 tiles without split-K).
// Workspace (peak 50.33 MB):
//   srcb/x1b bf16 [0,        8388608)   (LN1 in-place over srcb)
//   qkv  bf16     [8388608,  33554432)  dead after attn
//   ctx  bf16     [33554432, 41943040)  dead after out-proj
//   attnb bf16    [8388608,  16777216)  (reuse qkv)  dead after LN1
//   ff1  bf16     [8388608,  41943040)
//   wslot bf16    [41943040, 50331648)  converted weight (serial reuse)
// ---------------------------------------------------------------------------

typedef __attribute__((ext_vector_type(8))) short short8;   // 8 x bf16 MFMA frag
typedef __attribute__((ext_vector_type(4))) float f32x4;    // MFMA accumulator

__device__ __forceinline__ float b2f(unsigned short u) {
  union { unsigned int i; float f; } x; x.i = ((unsigned int)u) << 16; return x.f;
}
__device__ __forceinline__ unsigned short f2b(float f) {
  union { float f; unsigned int i; } x; x.f = f;
  unsigned int i = x.i;
  unsigned int r = (i + 0x7FFFu + ((i >> 16) & 1u)) >> 16;  // RNE
  return (unsigned short)r;
}
__device__ __forceinline__ uint4 pack8(float4 f0, float4 f1) {
  uint4 r;
  r.x = (unsigned)f2b(f0.x) | ((unsigned)f2b(f0.y) << 16);
  r.y = (unsigned)f2b(f0.z) | ((unsigned)f2b(f0.w) << 16);
  r.z = (unsigned)f2b(f1.x) | ((unsigned)f2b(f1.y) << 16);
  r.w = (unsigned)f2b(f1.z) | ((unsigned)f2b(f1.w) << 16);
  return r;
}

// async global->LDS, 16B/lane; LDS base wave-uniform, lanes write base+lane*16
__device__ __forceinline__ void gl_lds16(const unsigned short* g, unsigned short* l) {
  __builtin_amdgcn_global_load_lds(
      (const __attribute__((address_space(1))) unsigned int*)g,
      (__attribute__((address_space(3))) unsigned int*)l, 16, 0, 0);
}

// ---------------------------------------------------------------------------
// f32 -> bf16 convert
// ---------------------------------------------------------------------------
__global__ __launch_bounds__(256) void conv_k(
    const float* __restrict__ in, unsigned short* __restrict__ out, int n)
{
  const int i = (blockIdx.x * 256 + threadIdx.x) * 8;
  if (i < n) {
    const float4 f0 = *(const float4*)(in + i);
    const float4 f1 = *(const float4*)(in + i + 4);
    *(uint4*)(out + i) = pack8(f0, f1);
  }
}

// ---------------------------------------------------------------------------
// GEMM 256x256 tile, BK=64: out[M,N] = A[M,K] @ W[N,K]^T + bias. bf16 in.
// 512 threads = 8 waves (2M x 4N); per-wave output 128x64 (mt=8, nt=4).
// LDS 128 KB: As[2][256*64] + Bs[2][256*64]. r-rotation chunk swizzle
// (slot s of row r holds chunk c=(s+r)&7; reader of chunk c uses slot
// (c-r)&7) -- conflict-free, proven in R10-R14 kernels.
// Counted-vmcnt 2-deep pipeline: 8 gl_lds per tile per thread; steady
// wait vmcnt(8) so next tile's loads stay in flight across barriers.
// Per step: vmcnt;bar1; read B(8)+A-half1(8); MFMA 32 (covers half2 reads);
// read A-half2(8); lgkm0;bar2; stage s+2; MFMA 32 (reg-only, overlaps DMA).
// ---------------------------------------------------------------------------
template<int RELU, int OUT32>
__global__ __launch_bounds__(512, 2) void gemm256(
    const unsigned short* __restrict__ A, const unsigned short* __restrict__ Wb,
    const float* __restrict__ bias, void* __restrict__ out,
    int M, int N, int K)
{
  __shared__ unsigned short As[2][256 * 64];   // 64 KB
  __shared__ unsigned short Bs[2][256 * 64];   // 64 KB

  const int tid = threadIdx.x;
  const int lane = tid & 63, wid = tid >> 6;
  const int wm = wid >> 2, wn = wid & 3;       // wave grid 2M x 4N

  // XCD-aware bijective remap (total blocks % 8 == 0: 192 / 256)
  const int gx = gridDim.x;
  const int flat = blockIdx.y * gx + blockIdx.x;
  const int chunk = (gx * gridDim.y) >> 3;
  const int nf = (flat & 7) * chunk + (flat >> 3);
  const int m0 = (nf / gx) * 256, n0 = (nf % gx) * 256;

  // staging: 2048 16B-slots per matrix; thread handles slots i*512+tid
  const unsigned short* gA[4];
  const unsigned short* gW[4];
  int ldsO[4];
#pragma unroll
  for (int i = 0; i < 4; ++i) {
    const int sbase = i * 512 + (tid & ~63);   // wave-uniform slot base
    const int sl = sbase + lane;
    const int r = sl >> 3, s = sl & 7, c = (s + r) & 7;
    gA[i] = A + (size_t)(m0 + r) * K + c * 8;
    gW[i] = Wb + (size_t)(n0 + r) * K + c * 8;
    ldsO[i] = sbase * 8;                       // elements (16B per slot)
  }

  const int cl = lane & 15;
  const int kg = lane >> 4;

  f32x4 acc[8][4];
#pragma unroll
  for (int i = 0; i < 8; ++i)
#pragma unroll
    for (int j = 0; j < 4; ++j) acc[i][j] = (f32x4){0.f, 0.f, 0.f, 0.f};

  const int steps = K >> 6;

  // prologue: stage tiles 0,1 into buffers 0,1 (8 loads each per thread)
  const int pre = steps < 2 ? steps : 2;
  for (int t = 0; t < pre; ++t) {
#pragma unroll
    for (int i = 0; i < 4; ++i) { gl_lds16(gA[i], &As[t][ldsO[i]]); gA[i] += 64; }
#pragma unroll
    for (int i = 0; i < 4; ++i) { gl_lds16(gW[i], &Bs[t][ldsO[i]]); gW[i] += 64; }
  }

  int cur = 0;
  for (int s = 0; s < steps; ++s) {
    // wait for tile s only; tile s+1's 8 loads stay in flight across barrier
    if (s + 1 < steps) asm volatile("s_waitcnt vmcnt(8)" ::: "memory");
    else               asm volatile("s_waitcnt vmcnt(0)" ::: "memory");
    __builtin_amdgcn_s_barrier();   // all waves' tile-s loads now in LDS

    // B fragments (4 nt x 2 ks = 8 ds_read_b128)
    short8 bf[4][2];
#pragma unroll
    for (int nt = 0; nt < 4; ++nt)
#pragma unroll
      for (int ks = 0; ks < 2; ++ks) {
        const int br = wn * 64 + nt * 16 + cl;
        bf[nt][ks] = *(const short8*)&Bs[cur][br * 64 + (((ks * 4 + kg) - br) & 7) * 8];
      }
    // A fragments, first half (mt 0..3)
    short8 af[4][2];
#pragma unroll
    for (int mt = 0; mt < 4; ++mt)
#pragma unroll
      for (int ks = 0; ks < 2; ++ks) {
        const int ar = wm * 128 + mt * 16 + cl;
        af[mt][ks] = *(const short8*)&As[cur][ar * 64 + (((ks * 4 + kg) - ar) & 7) * 8];
      }

    __builtin_amdgcn_s_setprio(1);
#pragma unroll
    for (int mt = 0; mt < 4; ++mt)
#pragma unroll
      for (int nt = 0; nt < 4; ++nt)
#pragma unroll
        for (int ks = 0; ks < 2; ++ks)
          acc[mt][nt] = __builtin_amdgcn_mfma_f32_16x16x32_bf16(af[mt][ks], bf[nt][ks], acc[mt][nt], 0, 0, 0);
    __builtin_amdgcn_s_setprio(0);

    // A fragments, second half (mt 4..7) -> reuse af regs
    short8 ag[4][2];
#pragma unroll
    for (int mt = 0; mt < 4; ++mt)
#pragma unroll
      for (int ks = 0; ks < 2; ++ks) {
        const int ar = wm * 128 + (mt + 4) * 16 + cl;
        ag[mt][ks] = *(const short8*)&As[cur][ar * 64 + (((ks * 4 + kg) - ar) & 7) * 8];
      }

    asm volatile("s_waitcnt lgkmcnt(0)" ::: "memory");  // all frag reads retired
    __builtin_amdgcn_sched_barrier(0);
    __builtin_amdgcn_s_barrier();   // everyone done reading buf[cur]

    if (s + 2 < steps) {            // stage tile s+2 into just-freed buffer
#pragma unroll
      for (int i = 0; i < 4; ++i) { gl_lds16(gA[i], &As[cur][ldsO[i]]); gA[i] += 64; }
#pragma unroll
      for (int i = 0; i < 4; ++i) { gl_lds16(gW[i], &Bs[cur][ldsO[i]]); gW[i] += 64; }
    }

    __builtin_amdgcn_s_setprio(1);
#pragma unroll
    for (int mt = 0; mt < 4; ++mt)
#pragma unroll
      for (int nt = 0; nt < 4; ++nt)
#pragma unroll
        for (int ks = 0; ks < 2; ++ks)
          acc[mt + 4][nt] = __builtin_amdgcn_mfma_f32_16x16x32_bf16(ag[mt][ks], bf[nt][ks], acc[mt + 4][nt], 0, 0, 0);
    __builtin_amdgcn_s_setprio(0);

    cur ^= 1;
  }

  // epilogue: C/D mapping col = cl, row = kg*4 + r  [m89-verified]
#pragma unroll
  for (int nt = 0; nt < 4; ++nt) {
    const int col = n0 + wn * 64 + nt * 16 + cl;
    const float bvs = bias[col];
#pragma unroll
    for (int mt = 0; mt < 8; ++mt) {
#pragma unroll
      for (int r = 0; r < 4; ++r) {
        const int grow = m0 + wm * 128 + mt * 16 + kg * 4 + r;
        float v = acc[mt][nt][r] + bvs;
        if (RELU) v = fmaxf(v, 0.f);
        if (OUT32) ((float*)out)[(size_t)grow * N + col] = v;
        else       ((unsigned short*)out)[(size_t)grow * N + col] = f2b(v);
      }
    }
  }
}

// ---------------------------------------------------------------------------
// GEMM 64x128 tile, BK=64 — N=1024 shapes (grid 512 = 2 blocks/CU).
// R12-exact: 3-deep counted-vmcnt pipeline (72 KB LDS), no ks-split, no
// setprio (both measured as regressions in R13). XCD-chunked bijective
// blockIdx remap (requires nwg % 8 == 0 — true for both (8,64) call sites).
// ---------------------------------------------------------------------------
template<int OUT32>
__global__ __launch_bounds__(256) void gemm64(
    const unsigned short* __restrict__ A, const unsigned short* __restrict__ Wb,
    const float* __restrict__ bias, void* __restrict__ out,
    int M, int N, int K)
{
  __shared__ unsigned short As[3][64 * 64];    // 24 KB
  __shared__ unsigned short Bs[3][128 * 64];   // 48 KB

  const int tid = threadIdx.x;
  const int lane = tid & 63, wid = tid >> 6;

  const int nwgx = gridDim.x;
  const int flat = blockIdx.y * nwgx + blockIdx.x;
  const int chunk = (nwgx * gridDim.y) >> 3;
  const int nf = (flat & 7) * chunk + (flat >> 3);
  const int m0 = (nf / nwgx) * 64, n0 = (nf % nwgx) * 128;

  const unsigned short* gA[2];
  const unsigned short* gW[4];
  int ldsA[2], ldsB[4];
#pragma unroll
  for (int i = 0; i < 2; ++i) {
    const int sl = wid * 128 + i * 64 + lane;
    const int r = sl >> 3, s = sl & 7, c = (s + r) & 7;
    gA[i] = A + (size_t)(m0 + r) * K + c * 8;
    ldsA[i] = (wid * 128 + i * 64) * 8;
  }
#pragma unroll
  for (int i = 0; i < 4; ++i) {
    const int sl = wid * 256 + i * 64 + lane;
    const int r = sl >> 3, s = sl & 7, c = (s + r) & 7;
    gW[i] = Wb + (size_t)(n0 + r) * K + c * 8;
    ldsB[i] = (wid * 256 + i * 64) * 8;
  }

  const int cl = lane & 15;
  const int kg = lane >> 4;
  int aoff[4][2], boff[2][2];
#pragma unroll
  for (int t = 0; t < 4; ++t) {
    const int ar = t * 16 + cl;
#pragma unroll
    for (int ks = 0; ks < 2; ++ks)
      aoff[t][ks] = ar * 64 + ((ks * 4 + kg - ar) & 7) * 8;
  }
#pragma unroll
  for (int t = 0; t < 2; ++t) {
    const int br = wid * 32 + t * 16 + cl;
#pragma unroll
    for (int ks = 0; ks < 2; ++ks)
      boff[t][ks] = br * 64 + ((ks * 4 + kg - br) & 7) * 8;
  }

  f32x4 acc[4][2];
#pragma unroll
  for (int i = 0; i < 4; ++i)
#pragma unroll
    for (int j = 0; j < 2; ++j) acc[i][j] = (f32x4){0.f, 0.f, 0.f, 0.f};

  const int steps = K >> 6;

  const int pre = steps < 3 ? steps : 3;
  for (int t = 0; t < pre; ++t) {
#pragma unroll
    for (int i = 0; i < 2; ++i) { gl_lds16(gA[i], &As[t][ldsA[i]]); gA[i] += 64; }
#pragma unroll
    for (int i = 0; i < 4; ++i) { gl_lds16(gW[i], &Bs[t][ldsB[i]]); gW[i] += 64; }
  }

  int cur = 0;
  for (int s = 0; s < steps; ++s) {
    const int rem = steps - 1 - s;
    if (rem >= 2)      asm volatile("s_waitcnt vmcnt(12)" ::: "memory");
    else if (rem == 1) asm volatile("s_waitcnt vmcnt(6)" ::: "memory");
    else               asm volatile("s_waitcnt vmcnt(0)" ::: "memory");
    __builtin_amdgcn_s_barrier();

    short8 af[4][2], bf[2][2];
#pragma unroll
    for (int t = 0; t < 4; ++t)
#pragma unroll
      for (int ks = 0; ks < 2; ++ks) af[t][ks] = *(const short8*)&As[cur][aoff[t][ks]];
#pragma unroll
    for (int t = 0; t < 2; ++t)
#pragma unroll
      for (int ks = 0; ks < 2; ++ks) bf[t][ks] = *(const short8*)&Bs[cur][boff[t][ks]];

    asm volatile("s_waitcnt lgkmcnt(0)" ::: "memory");
    __builtin_amdgcn_sched_barrier(0);
    __builtin_amdgcn_s_barrier();

    if (s + 3 < steps) {
#pragma unroll
      for (int i = 0; i < 2; ++i) { gl_lds16(gA[i], &As[cur][ldsA[i]]); gA[i] += 64; }
#pragma unroll
      for (int i = 0; i < 4; ++i) { gl_lds16(gW[i], &Bs[cur][ldsB[i]]); gW[i] += 64; }
    }

#pragma unroll
    for (int mt = 0; mt < 4; ++mt)
#pragma unroll
      for (int nt = 0; nt < 2; ++nt)
#pragma unroll
        for (int ks = 0; ks < 2; ++ks)
          acc[mt][nt] = __builtin_amdgcn_mfma_f32_16x16x32_bf16(af[mt][ks], bf[nt][ks], acc[mt][nt], 0, 0, 0);

    cur = (cur == 2) ? 0 : cur + 1;
  }

#pragma unroll
  for (int nt = 0; nt < 2; ++nt) {
    const int col = n0 + wid * 32 + nt * 16 + cl;
    const float bvs = bias[col];
#pragma unroll
    for (int mt = 0; mt < 4; ++mt) {
#pragma unroll
      for (int r = 0; r < 4; ++r) {
        const int grow = m0 + mt * 16 + kg * 4 + r;
        const float v = acc[mt][nt][r] + bvs;
        if (OUT32) ((float*)out)[(size_t)grow * N + col] = v;
        else       ((unsigned short*)out)[(size_t)grow * N + col] = f2b(v);
      }
    }
  }
}

// ---------------------------------------------------------------------------
// MFMA flash attention (unchanged from passing r6-r9).
// ---------------------------------------------------------------------------
__global__ __launch_bounds__(256) void attn_mfma(
    const unsigned short* __restrict__ qkv, unsigned short* __restrict__ ctx)
{
  __shared__ unsigned short Ks[64 * 72];
  __shared__ unsigned short Vt[64 * 72];
  __shared__ unsigned short Ps[64 * 72];

  const int tid = threadIdx.x;
  const int bid = blockIdx.x;
  const int qt = bid & 31, h = (bid >> 5) & 15, b = bid >> 9;
  const int q0 = qt * 64;
  const int wstart = max(0, q0 - 128);
  const int wend = min(2048, q0 + 64 + 128);
  const int ntile = (wend - wstart + 63) >> 6;
  const size_t rowb = (size_t)b * 2048;

  const int lane = tid & 63, wid = tid >> 6;
  const int cl = lane & 15;
  const int kq = (lane >> 4) * 8;
  const int rowg = lane >> 4;

  short8 aQ[2];
#pragma unroll
  for (int ks = 0; ks < 2; ++ks)
    aQ[ks] = *(const short8*)(qkv + (rowb + q0 + wid * 16 + cl) * 3072 + h * 64 + ks * 32 + kq);

  float m_i[4], l_i[4];
  f32x4 O[4];
#pragma unroll
  for (int r = 0; r < 4; ++r) { m_i[r] = -1.0e30f; l_i[r] = 0.f; }
#pragma unroll
  for (int nt = 0; nt < 4; ++nt) O[nt] = (f32x4){0.f, 0.f, 0.f, 0.f};

  for (int t = 0; t < ntile; ++t) {
    const int jbase = wstart + t * 64;
    __syncthreads();
    for (int idx = tid; idx < 512; idx += 256) {
      const int r = idx >> 3, c = idx & 7;
      const int jg = jbase + r;
      uint4 kv = {0u, 0u, 0u, 0u}, vv = {0u, 0u, 0u, 0u};
      if (jg < wend) {
        const size_t base = (rowb + jg) * 3072 + h * 64 + c * 8;
        kv = *(const uint4*)(qkv + base + 1024);
        vv = *(const uint4*)(qkv + base + 2048);
      }
      *(uint4*)&Ks[r * 72 + c * 8] = kv;
      const unsigned short* vs = (const unsigned short*)&vv;
#pragma unroll
      for (int ii = 0; ii < 8; ++ii) Vt[(c * 8 + ii) * 72 + r] = vs[ii];
    }
    __syncthreads();

    f32x4 S[4];
#pragma unroll
    for (int nt = 0; nt < 4; ++nt) S[nt] = (f32x4){0.f, 0.f, 0.f, 0.f};
#pragma unroll
    for (int nt = 0; nt < 4; ++nt)
#pragma unroll
      for (int ks = 0; ks < 2; ++ks) {
        const short8 bK = *(const short8*)&Ks[(nt * 16 + cl) * 72 + ks * 32 + kq];
        S[nt] = __builtin_amdgcn_mfma_f32_16x16x32_bf16(aQ[ks], bK, S[nt], 0, 0, 0);
      }

    float sc[4][4];
#pragma unroll
    for (int nt = 0; nt < 4; ++nt) {
      const int jg = jbase + nt * 16 + cl;
#pragma unroll
      for (int r = 0; r < 4; ++r) {
        const int i = q0 + wid * 16 + rowg * 4 + r;
        const bool v = (jg < wend) && (jg >= i - 128) && (jg <= i + 128);
        sc[nt][r] = v ? S[nt][r] * 0.125f : -1.0e30f;
      }
    }

    float alpha[4], p[4][4];
#pragma unroll
    for (int r = 0; r < 4; ++r) {
      float tm = fmaxf(fmaxf(sc[0][r], sc[1][r]), fmaxf(sc[2][r], sc[3][r]));
      tm = fmaxf(tm, __shfl_xor(tm, 1, 64));
      tm = fmaxf(tm, __shfl_xor(tm, 2, 64));
      tm = fmaxf(tm, __shfl_xor(tm, 4, 64));
      tm = fmaxf(tm, __shfl_xor(tm, 8, 64));
      const float mn = fmaxf(m_i[r], tm);
      alpha[r] = __expf(m_i[r] - mn);
      m_i[r] = mn;
      float ps = 0.f;
#pragma unroll
      for (int nt = 0; nt < 4; ++nt) { p[nt][r] = __expf(sc[nt][r] - mn); ps += p[nt][r]; }
      ps += __shfl_xor(ps, 1, 64);
      ps += __shfl_xor(ps, 2, 64);
      ps += __shfl_xor(ps, 4, 64);
      ps += __shfl_xor(ps, 8, 64);
      l_i[r] = l_i[r] * alpha[r] + ps;
    }

#pragma unroll
    for (int nt = 0; nt < 4; ++nt)
#pragma unroll
      for (int r = 0; r < 4; ++r)
        Ps[(wid * 16 + rowg * 4 + r) * 72 + nt * 16 + cl] = f2b(p[nt][r]);
    __syncthreads();

#pragma unroll
    for (int nt = 0; nt < 4; ++nt)
#pragma unroll
      for (int r = 0; r < 4; ++r) O[nt][r] *= alpha[r];
    short8 aP[2];
#pragma unroll
    for (int ks = 0; ks < 2; ++ks)
      aP[ks] = *(const short8*)&Ps[(wid * 16 + cl) * 72 + ks * 32 + kq];
#pragma unroll
    for (int nt = 0; nt < 4; ++nt)
#pragma unroll
      for (int ks = 0; ks < 2; ++ks) {
        const short8 bV = *(const short8*)&Vt[(nt * 16 + cl) * 72 + ks * 32 + kq];
        O[nt] = __builtin_amdgcn_mfma_f32_16x16x32_bf16(aP[ks], bV, O[nt], 0, 0, 0);
      }
  }

#pragma unroll
  for (int nt = 0; nt < 4; ++nt) {
    const int d = nt * 16 + cl;
#pragma unroll
    for (int r = 0; r < 4; ++r) {
      const int i = q0 + wid * 16 + rowg * 4 + r;
      ctx[(rowb + i) * 1024 + h * 64 + d] = f2b(O[nt][r] / l_i[r]);
    }
  }
}

// ---------------------------------------------------------------------------
// Residual + LayerNorm (unchanged). In-place safe per-row.
// ---------------------------------------------------------------------------
template<int AF32, int BF32, int OF32>
__global__ __launch_bounds__(256) void ln_k(
    const void* __restrict__ a, const void* __restrict__ b,
    const float* __restrict__ g, const float* __restrict__ be,
    void* __restrict__ o)
{
  __shared__ float rbuf[8];
  const int tid = threadIdx.x;
  const size_t base = (size_t)blockIdx.x * 1024;
  const int lane = tid & 63, wid = tid >> 6;

  float xv[4], s = 0.f, sq = 0.f;
#pragma unroll
  for (int t = 0; t < 4; ++t) {
    const int c = tid + t * 256;
    const float av = AF32 ? ((const float*)a)[base + c]
                          : b2f(((const unsigned short*)a)[base + c]);
    const float bv = BF32 ? ((const float*)b)[base + c]
                          : b2f(((const unsigned short*)b)[base + c]);
    const float x = av + bv;
    xv[t] = x; s += x; sq += x * x;
  }
  for (int o2 = 1; o2 < 64; o2 <<= 1) { s += __shfl_xor(s, o2, 64); sq += __shfl_xor(sq, o2, 64); }
  if (lane == 0) { rbuf[wid] = s; rbuf[wid + 4] = sq; }
  __syncthreads();
  s  = rbuf[0] + rbuf[1] + rbuf[2] + rbuf[3];
  sq = rbuf[4] + rbuf[5] + rbuf[6] + rbuf[7];
  const float mean = s * (1.0f / 1024.f);
  const float var = sq * (1.0f / 1024.f) - mean * mean;
  const float rstd = rsqrtf(var + 1e-5f);
#pragma unroll
  for (int t = 0; t < 4; ++t) {
    const int c = tid + t * 256;
    const float y = (xv[t] - mean) * rstd * g[c] + be[c];
    if (OF32) ((float*)o)[base + c] = y;
    else      ((unsigned short*)o)[base + c] = f2b(y);
  }
}

// ---------------------------------------------------------------------------
extern "C" void kernel_launch(void* const* d_in, const int* in_sizes, int n_in,
                              void* d_out, int out_size, void* d_ws, size_t ws_size,
                              hipStream_t stream)
{
  (void)in_sizes; (void)n_in; (void)out_size; (void)ws_size;
  const float* src   = (const float*)d_in[0];
  const float* w_in  = (const float*)d_in[1];
  const float* b_in  = (const float*)d_in[2];
  const float* w_out = (const float*)d_in[3];
  const float* b_out = (const float*)d_in[4];
  const float* w1    = (const float*)d_in[5];
  const float* b1    = (const float*)d_in[6];
  const float* w2    = (const float*)d_in[7];
  const float* b2    = (const float*)d_in[8];
  const float* g1    = (const float*)d_in[9];
  const float* be1   = (const float*)d_in[10];
  const float* g2    = (const float*)d_in[11];
  const float* be2   = (const float*)d_in[12];

  char* ws = (char*)d_ws;
  unsigned short* srcb  = (unsigned short*)(ws);                 // [0, 8388608)
  unsigned short* x1b   = srcb;                                  // in-place over srcb
  unsigned short* qkv   = (unsigned short*)(ws + 8388608);       // [8388608, 33554432)
  unsigned short* ctx   = (unsigned short*)(ws + 33554432);      // [33554432, 41943040)
  unsigned short* attnb = (unsigned short*)(ws + 8388608);       // reuse qkv head
  unsigned short* ff1   = (unsigned short*)(ws + 8388608);       // [8388608, 41943040)
  unsigned short* wslot = (unsigned short*)(ws + 41943040);      // [41943040, 50331648)
  float*          outf  = (float*)d_out;

  // 0) convert src -> bf16 srcb
  conv_k<<<dim3(2048), 256, 0, stream>>>(src, srcb, 4194304);
  // 1) convert in_proj_w; QKV projection (gemm256, grid 192) -> bf16 qkv
  conv_k<<<dim3(1536), 256, 0, stream>>>(w_in, wslot, 3145728);
  gemm256<0, 0><<<dim3(12, 16), 512, 0, stream>>>(srcb, wslot, b_in, qkv, 4096, 3072, 1024);
  // 2) banded MFMA flash attention -> bf16 ctx
  attn_mfma<<<dim3(1024), 256, 0, stream>>>(qkv, ctx);
  // 3) convert out_w; output projection (gemm64) -> bf16 attnb
  conv_k<<<dim3(512), 256, 0, stream>>>(w_out, wslot, 1048576);
  gemm64<0><<<dim3(8, 64), 256, 0, stream>>>(ctx, wslot, b_out, attnb, 4096, 1024, 1024);
  // 4) LN1(srcb bf16 + attnb bf16) -> bf16 x1b (in-place over srcb)
  ln_k<0, 0, 0><<<dim3(4096), 256, 0, stream>>>(srcb, attnb, g1, be1, x1b);
  // 5) convert lin1_w; FF1 + ReLU (gemm256, grid 256 = 1/CU) -> bf16 ff1
  conv_k<<<dim3(2048), 256, 0, stream>>>(w1, wslot, 4194304);
  gemm256<1, 0><<<dim3(16, 16), 512, 0, stream>>>(x1b, wslot, b1, ff1, 4096, 4096, 1024);
  // 6) convert lin2_w; FF2 (gemm64) -> f32 into d_out
  conv_k<<<dim3(2048), 256, 0, stream>>>(w2, wslot, 4194304);
  gemm64<1><<<dim3(8, 64), 256, 0, stream>>>(ff1, wslot, b2, outf, 4096, 1024, 4096);
  // 7) LN2(x1b bf16 + d_out f32) -> f32 d_out (in-place, per-row safe)
  ln_k<0, 1, 1><<<dim3(4096), 256, 0, stream>>>(x1b, outf, g2, be2, outf);
}

// Round 6
// 308.803 us; speedup vs baseline: 1.0676x; 1.0102x over previous
//
#include <hip/hip_runtime.h>
#include <cstdint>
#include <cstddef>

// ---------------------------------------------------------------------------
// RestrictedTransformerEncoderLayer on MI355X (gfx950)  — ROUND 16
// B=2, L=2048, E=1024, H=16, D=64, FF=4096, WIN=128.
// External I/O f32; intermediates bf16; output f32.
// R16: FF2 gemm64 is LDS-pipe-bound (per block-step: 4 waves x 12KB reads
// [A rows read 4x redundantly] + 24KB DMA = 72KB; 9.2MB/CU ~ 108Kcy floor ~
// measured 117Kcy). Fix = re-partition: 64x128 tile with TWO waves of 64x64
// (A redundancy 4x->2x, 0.5 reads/MFMA): 56KB/step (-22%). Same R12 3-deep
// counted-vmcnt pipeline, 128 threads, 12 gl_lds/thread/tile -> vmcnt(24).
// Also: fused conv3_k (src + w_in + w_out in one launch; w_in+w_out pack
// exactly into wslot's 4,194,304 elems). 12 -> 10 launches.
// gemm256 (QKV/FF1) unchanged — R15 moved both out of the top-5.
// Workspace (peak 50.33 MB):
//   srcb/x1b bf16 [0,        8388608)   (LN1 in-place over srcb)
//   qkv  bf16     [8388608,  33554432)  dead after attn
//   ctx  bf16     [33554432, 41943040)  dead after out-proj
//   attnb bf16    [8388608,  16777216)  (reuse qkv)  dead after LN1
//   ff1  bf16     [8388608,  41943040)
//   wslot bf16    [41943040, 50331648)  w_in[0,3145728)+w_out[3145728,..);
//                                       later w1, then w2 (serial reuse)
// ---------------------------------------------------------------------------

typedef __attribute__((ext_vector_type(8))) short short8;   // 8 x bf16 MFMA frag
typedef __attribute__((ext_vector_type(4))) float f32x4;    // MFMA accumulator

__device__ __forceinline__ float b2f(unsigned short u) {
  union { unsigned int i; float f; } x; x.i = ((unsigned int)u) << 16; return x.f;
}
__device__ __forceinline__ unsigned short f2b(float f) {
  union { float f; unsigned int i; } x; x.f = f;
  unsigned int i = x.i;
  unsigned int r = (i + 0x7FFFu + ((i >> 16) & 1u)) >> 16;  // RNE
  return (unsigned short)r;
}
__device__ __forceinline__ uint4 pack8(float4 f0, float4 f1) {
  uint4 r;
  r.x = (unsigned)f2b(f0.x) | ((unsigned)f2b(f0.y) << 16);
  r.y = (unsigned)f2b(f0.z) | ((unsigned)f2b(f0.w) << 16);
  r.z = (unsigned)f2b(f1.x) | ((unsigned)f2b(f1.y) << 16);
  r.w = (unsigned)f2b(f1.z) | ((unsigned)f2b(f1.w) << 16);
  return r;
}

// async global->LDS, 16B/lane; LDS base wave-uniform, lanes write base+lane*16
__device__ __forceinline__ void gl_lds16(const unsigned short* g, unsigned short* l) {
  __builtin_amdgcn_global_load_lds(
      (const __attribute__((address_space(1))) unsigned int*)g,
      (__attribute__((address_space(3))) unsigned int*)l, 16, 0, 0);
}

// ---------------------------------------------------------------------------
// f32 -> bf16 convert (single array)
// ---------------------------------------------------------------------------
__global__ __launch_bounds__(256) void conv_k(
    const float* __restrict__ in, unsigned short* __restrict__ out, int n)
{
  const int i = (blockIdx.x * 256 + threadIdx.x) * 8;
  if (i < n) {
    const float4 f0 = *(const float4*)(in + i);
    const float4 f1 = *(const float4*)(in + i + 4);
    *(uint4*)(out + i) = pack8(f0, f1);
  }
}

// ---------------------------------------------------------------------------
// Fused convert: src (4194304) -> srcb; w_in (3145728) + w_out (1048576)
// -> wslot packed [w_in | w_out]. Total 8388608 elems, grid 4096 x 256.
// Boundaries are multiples of 8 -> no straddle.
// ---------------------------------------------------------------------------
__global__ __launch_bounds__(256) void conv3_k(
    const float* __restrict__ src, unsigned short* __restrict__ srcb,
    const float* __restrict__ w_in, const float* __restrict__ w_out,
    unsigned short* __restrict__ wslot)
{
  const int i = (blockIdx.x * 256 + threadIdx.x) * 8;
  const float* in;
  unsigned short* out;
  if (i < 4194304)      { in = src + i;                 out = srcb + i; }
  else if (i < 7340032) { in = w_in + (i - 4194304);    out = wslot + (i - 4194304); }
  else                  { in = w_out + (i - 7340032);   out = wslot + (i - 4194304); }
  const float4 f0 = *(const float4*)(in);
  const float4 f1 = *(const float4*)(in + 4);
  *(uint4*)(out) = pack8(f0, f1);
}

// ---------------------------------------------------------------------------
// GEMM 256x256 tile, BK=64 (unchanged from R15 — moved QKV/FF1 off top-5).
// 512 threads = 8 waves (2M x 4N); per-wave output 128x64. 128 KB LDS 2-dbuf,
// counted vmcnt(8), r-rotation conflict-free swizzle.
// ---------------------------------------------------------------------------
template<int RELU, int OUT32>
__global__ __launch_bounds__(512, 2) void gemm256(
    const unsigned short* __restrict__ A, const unsigned short* __restrict__ Wb,
    const float* __restrict__ bias, void* __restrict__ out,
    int M, int N, int K)
{
  __shared__ unsigned short As[2][256 * 64];   // 64 KB
  __shared__ unsigned short Bs[2][256 * 64];   // 64 KB

  const int tid = threadIdx.x;
  const int lane = tid & 63, wid = tid >> 6;
  const int wm = wid >> 2, wn = wid & 3;       // wave grid 2M x 4N

  const int gx = gridDim.x;
  const int flat = blockIdx.y * gx + blockIdx.x;
  const int chunk = (gx * gridDim.y) >> 3;
  const int nf = (flat & 7) * chunk + (flat >> 3);
  const int m0 = (nf / gx) * 256, n0 = (nf % gx) * 256;

  const unsigned short* gA[4];
  const unsigned short* gW[4];
  int ldsO[4];
#pragma unroll
  for (int i = 0; i < 4; ++i) {
    const int sbase = i * 512 + (tid & ~63);   // wave-uniform slot base
    const int sl = sbase + lane;
    const int r = sl >> 3, s = sl & 7, c = (s + r) & 7;
    gA[i] = A + (size_t)(m0 + r) * K + c * 8;
    gW[i] = Wb + (size_t)(n0 + r) * K + c * 8;
    ldsO[i] = sbase * 8;
  }

  const int cl = lane & 15;
  const int kg = lane >> 4;

  f32x4 acc[8][4];
#pragma unroll
  for (int i = 0; i < 8; ++i)
#pragma unroll
    for (int j = 0; j < 4; ++j) acc[i][j] = (f32x4){0.f, 0.f, 0.f, 0.f};

  const int steps = K >> 6;

  const int pre = steps < 2 ? steps : 2;
  for (int t = 0; t < pre; ++t) {
#pragma unroll
    for (int i = 0; i < 4; ++i) { gl_lds16(gA[i], &As[t][ldsO[i]]); gA[i] += 64; }
#pragma unroll
    for (int i = 0; i < 4; ++i) { gl_lds16(gW[i], &Bs[t][ldsO[i]]); gW[i] += 64; }
  }

  int cur = 0;
  for (int s = 0; s < steps; ++s) {
    if (s + 1 < steps) asm volatile("s_waitcnt vmcnt(8)" ::: "memory");
    else               asm volatile("s_waitcnt vmcnt(0)" ::: "memory");
    __builtin_amdgcn_s_barrier();

    short8 bf[4][2];
#pragma unroll
    for (int nt = 0; nt < 4; ++nt)
#pragma unroll
      for (int ks = 0; ks < 2; ++ks) {
        const int br = wn * 64 + nt * 16 + cl;
        bf[nt][ks] = *(const short8*)&Bs[cur][br * 64 + (((ks * 4 + kg) - br) & 7) * 8];
      }
    short8 af[4][2];
#pragma unroll
    for (int mt = 0; mt < 4; ++mt)
#pragma unroll
      for (int ks = 0; ks < 2; ++ks) {
        const int ar = wm * 128 + mt * 16 + cl;
        af[mt][ks] = *(const short8*)&As[cur][ar * 64 + (((ks * 4 + kg) - ar) & 7) * 8];
      }

    __builtin_amdgcn_s_setprio(1);
#pragma unroll
    for (int mt = 0; mt < 4; ++mt)
#pragma unroll
      for (int nt = 0; nt < 4; ++nt)
#pragma unroll
        for (int ks = 0; ks < 2; ++ks)
          acc[mt][nt] = __builtin_amdgcn_mfma_f32_16x16x32_bf16(af[mt][ks], bf[nt][ks], acc[mt][nt], 0, 0, 0);
    __builtin_amdgcn_s_setprio(0);

    short8 ag[4][2];
#pragma unroll
    for (int mt = 0; mt < 4; ++mt)
#pragma unroll
      for (int ks = 0; ks < 2; ++ks) {
        const int ar = wm * 128 + (mt + 4) * 16 + cl;
        ag[mt][ks] = *(const short8*)&As[cur][ar * 64 + (((ks * 4 + kg) - ar) & 7) * 8];
      }

    asm volatile("s_waitcnt lgkmcnt(0)" ::: "memory");
    __builtin_amdgcn_sched_barrier(0);
    __builtin_amdgcn_s_barrier();

    if (s + 2 < steps) {
#pragma unroll
      for (int i = 0; i < 4; ++i) { gl_lds16(gA[i], &As[cur][ldsO[i]]); gA[i] += 64; }
#pragma unroll
      for (int i = 0; i < 4; ++i) { gl_lds16(gW[i], &Bs[cur][ldsO[i]]); gW[i] += 64; }
    }

    __builtin_amdgcn_s_setprio(1);
#pragma unroll
    for (int mt = 0; mt < 4; ++mt)
#pragma unroll
      for (int nt = 0; nt < 4; ++nt)
#pragma unroll
        for (int ks = 0; ks < 2; ++ks)
          acc[mt + 4][nt] = __builtin_amdgcn_mfma_f32_16x16x32_bf16(ag[mt][ks], bf[nt][ks], acc[mt + 4][nt], 0, 0, 0);
    __builtin_amdgcn_s_setprio(0);

    cur ^= 1;
  }

#pragma unroll
  for (int nt = 0; nt < 4; ++nt) {
    const int col = n0 + wn * 64 + nt * 16 + cl;
    const float bvs = bias[col];
#pragma unroll
    for (int mt = 0; mt < 8; ++mt) {
#pragma unroll
      for (int r = 0; r < 4; ++r) {
        const int grow = m0 + wm * 128 + mt * 16 + kg * 4 + r;
        float v = acc[mt][nt][r] + bvs;
        if (RELU) v = fmaxf(v, 0.f);
        if (OUT32) ((float*)out)[(size_t)grow * N + col] = v;
        else       ((unsigned short*)out)[(size_t)grow * N + col] = f2b(v);
      }
    }
  }
}

// ---------------------------------------------------------------------------
// GEMM 64x128 tile, BK=64 — N=1024 shapes (grid 512 = 2 blocks/CU).
// R16: re-partitioned to TWO waves of 64x64 (was 4 of 64x32): A-row LDS
// redundancy 4x->2x, per-step traffic 72->56KB (0.5 reads/MFMA). Same R12
// 3-deep counted-vmcnt pipeline; 128 threads; 12 gl_lds/thread/tile so
// steady-state wait = vmcnt(24) (2 newer tiles in flight), tail 12->0.
// LDS 3 x 24KB = 72KB -> 2 blocks/CU. r-rotation swizzle (conflict-free).
// ---------------------------------------------------------------------------
template<int OUT32>
__global__ __launch_bounds__(128) void gemm64(
    const unsigned short* __restrict__ A, const unsigned short* __restrict__ Wb,
    const float* __restrict__ bias, void* __restrict__ out,
    int M, int N, int K)
{
  __shared__ unsigned short As[3][64 * 64];    // 24 KB
  __shared__ unsigned short Bs[3][128 * 64];   // 48 KB

  const int tid = threadIdx.x;
  const int lane = tid & 63, wid = tid >> 6;   // wid in {0,1}

  const int nwgx = gridDim.x;
  const int flat = blockIdx.y * nwgx + blockIdx.x;
  const int chunk = (nwgx * gridDim.y) >> 3;
  const int nf = (flat & 7) * chunk + (flat >> 3);
  const int m0 = (nf / nwgx) * 64, n0 = (nf % nwgx) * 128;

  // staging: As 512 slots (4/thread), Bs 1024 slots (8/thread)
  const unsigned short* gA[4];
  const unsigned short* gW[8];
  int ldsA[4], ldsB[8];
#pragma unroll
  for (int i = 0; i < 4; ++i) {
    const int sl = i * 128 + tid;
    const int r = sl >> 3, s = sl & 7, c = (s + r) & 7;
    gA[i] = A + (size_t)(m0 + r) * K + c * 8;
    ldsA[i] = (i * 128 + wid * 64) * 8;        // wave-uniform base
  }
#pragma unroll
  for (int i = 0; i < 8; ++i) {
    const int sl = i * 128 + tid;
    const int r = sl >> 3, s = sl & 7, c = (s + r) & 7;
    gW[i] = Wb + (size_t)(n0 + r) * K + c * 8;
    ldsB[i] = (i * 128 + wid * 64) * 8;
  }

  const int cl = lane & 15;
  const int kg = lane >> 4;
  int aoff[4][2], boff[4][2];
#pragma unroll
  for (int t = 0; t < 4; ++t) {
    const int ar = t * 16 + cl;                // A rows 0..63 (shared by waves)
    const int br = wid * 64 + t * 16 + cl;     // wave's own 64 B cols
#pragma unroll
    for (int ks = 0; ks < 2; ++ks) {
      aoff[t][ks] = ar * 64 + ((ks * 4 + kg - ar) & 7) * 8;
      boff[t][ks] = br * 64 + ((ks * 4 + kg - br) & 7) * 8;
    }
  }

  f32x4 acc[4][4];
#pragma unroll
  for (int i = 0; i < 4; ++i)
#pragma unroll
    for (int j = 0; j < 4; ++j) acc[i][j] = (f32x4){0.f, 0.f, 0.f, 0.f};

  const int steps = K >> 6;

  // prologue: stage up to 3 tiles (12 loads each per thread)
  const int pre = steps < 3 ? steps : 3;
  for (int t = 0; t < pre; ++t) {
#pragma unroll
    for (int i = 0; i < 4; ++i) { gl_lds16(gA[i], &As[t][ldsA[i]]); gA[i] += 64; }
#pragma unroll
    for (int i = 0; i < 8; ++i) { gl_lds16(gW[i], &Bs[t][ldsB[i]]); gW[i] += 64; }
  }

  int cur = 0;
  for (int s = 0; s < steps; ++s) {
    const int rem = steps - 1 - s;
    if (rem >= 2)      asm volatile("s_waitcnt vmcnt(24)" ::: "memory");
    else if (rem == 1) asm volatile("s_waitcnt vmcnt(12)" ::: "memory");
    else               asm volatile("s_waitcnt vmcnt(0)" ::: "memory");
    __builtin_amdgcn_s_barrier();   // tile s fully in LDS for all waves

    short8 af[4][2], bf[4][2];
#pragma unroll
    for (int t = 0; t < 4; ++t)
#pragma unroll
      for (int ks = 0; ks < 2; ++ks) {
        af[t][ks] = *(const short8*)&As[cur][aoff[t][ks]];
        bf[t][ks] = *(const short8*)&Bs[cur][boff[t][ks]];
      }

    asm volatile("s_waitcnt lgkmcnt(0)" ::: "memory");  // frag reads retired
    __builtin_amdgcn_sched_barrier(0);                  // rule #18 fence
    __builtin_amdgcn_s_barrier();   // everyone done reading buf[cur]

    if (s + 3 < steps) {            // stage tile s+3 into just-freed buffer
#pragma unroll
      for (int i = 0; i < 4; ++i) { gl_lds16(gA[i], &As[cur][ldsA[i]]); gA[i] += 64; }
#pragma unroll
      for (int i = 0; i < 8; ++i) { gl_lds16(gW[i], &Bs[cur][ldsB[i]]); gW[i] += 64; }
    }

#pragma unroll
    for (int mt = 0; mt < 4; ++mt)
#pragma unroll
      for (int nt = 0; nt < 4; ++nt)
#pragma unroll
        for (int ks = 0; ks < 2; ++ks)
          acc[mt][nt] = __builtin_amdgcn_mfma_f32_16x16x32_bf16(af[mt][ks], bf[nt][ks], acc[mt][nt], 0, 0, 0);

    cur = (cur == 2) ? 0 : cur + 1;
  }

#pragma unroll
  for (int nt = 0; nt < 4; ++nt) {
    const int col = n0 + wid * 64 + nt * 16 + cl;
    const float bvs = bias[col];
#pragma unroll
    for (int mt = 0; mt < 4; ++mt) {
#pragma unroll
      for (int r = 0; r < 4; ++r) {
        const int grow = m0 + mt * 16 + kg * 4 + r;
        const float v = acc[mt][nt][r] + bvs;
        if (OUT32) ((float*)out)[(size_t)grow * N + col] = v;
        else       ((unsigned short*)out)[(size_t)grow * N + col] = f2b(v);
      }
    }
  }
}

// ---------------------------------------------------------------------------
// MFMA flash attention (unchanged from passing r6-r9).
// ---------------------------------------------------------------------------
__global__ __launch_bounds__(256) void attn_mfma(
    const unsigned short* __restrict__ qkv, unsigned short* __restrict__ ctx)
{
  __shared__ unsigned short Ks[64 * 72];
  __shared__ unsigned short Vt[64 * 72];
  __shared__ unsigned short Ps[64 * 72];

  const int tid = threadIdx.x;
  const int bid = blockIdx.x;
  const int qt = bid & 31, h = (bid >> 5) & 15, b = bid >> 9;
  const int q0 = qt * 64;
  const int wstart = max(0, q0 - 128);
  const int wend = min(2048, q0 + 64 + 128);
  const int ntile = (wend - wstart + 63) >> 6;
  const size_t rowb = (size_t)b * 2048;

  const int lane = tid & 63, wid = tid >> 6;
  const int cl = lane & 15;
  const int kq = (lane >> 4) * 8;
  const int rowg = lane >> 4;

  short8 aQ[2];
#pragma unroll
  for (int ks = 0; ks < 2; ++ks)
    aQ[ks] = *(const short8*)(qkv + (rowb + q0 + wid * 16 + cl) * 3072 + h * 64 + ks * 32 + kq);

  float m_i[4], l_i[4];
  f32x4 O[4];
#pragma unroll
  for (int r = 0; r < 4; ++r) { m_i[r] = -1.0e30f; l_i[r] = 0.f; }
#pragma unroll
  for (int nt = 0; nt < 4; ++nt) O[nt] = (f32x4){0.f, 0.f, 0.f, 0.f};

  for (int t = 0; t < ntile; ++t) {
    const int jbase = wstart + t * 64;
    __syncthreads();
    for (int idx = tid; idx < 512; idx += 256) {
      const int r = idx >> 3, c = idx & 7;
      const int jg = jbase + r;
      uint4 kv = {0u, 0u, 0u, 0u}, vv = {0u, 0u, 0u, 0u};
      if (jg < wend) {
        const size_t base = (rowb + jg) * 3072 + h * 64 + c * 8;
        kv = *(const uint4*)(qkv + base + 1024);
        vv = *(const uint4*)(qkv + base + 2048);
      }
      *(uint4*)&Ks[r * 72 + c * 8] = kv;
      const unsigned short* vs = (const unsigned short*)&vv;
#pragma unroll
      for (int ii = 0; ii < 8; ++ii) Vt[(c * 8 + ii) * 72 + r] = vs[ii];
    }
    __syncthreads();

    f32x4 S[4];
#pragma unroll
    for (int nt = 0; nt < 4; ++nt) S[nt] = (f32x4){0.f, 0.f, 0.f, 0.f};
#pragma unroll
    for (int nt = 0; nt < 4; ++nt)
#pragma unroll
      for (int ks = 0; ks < 2; ++ks) {
        const short8 bK = *(const short8*)&Ks[(nt * 16 + cl) * 72 + ks * 32 + kq];
        S[nt] = __builtin_amdgcn_mfma_f32_16x16x32_bf16(aQ[ks], bK, S[nt], 0, 0, 0);
      }

    float sc[4][4];
#pragma unroll
    for (int nt = 0; nt < 4; ++nt) {
      const int jg = jbase + nt * 16 + cl;
#pragma unroll
      for (int r = 0; r < 4; ++r) {
        const int i = q0 + wid * 16 + rowg * 4 + r;
        const bool v = (jg < wend) && (jg >= i - 128) && (jg <= i + 128);
        sc[nt][r] = v ? S[nt][r] * 0.125f : -1.0e30f;
      }
    }

    float alpha[4], p[4][4];
#pragma unroll
    for (int r = 0; r < 4; ++r) {
      float tm = fmaxf(fmaxf(sc[0][r], sc[1][r]), fmaxf(sc[2][r], sc[3][r]));
      tm = fmaxf(tm, __shfl_xor(tm, 1, 64));
      tm = fmaxf(tm, __shfl_xor(tm, 2, 64));
      tm = fmaxf(tm, __shfl_xor(tm, 4, 64));
      tm = fmaxf(tm, __shfl_xor(tm, 8, 64));
      const float mn = fmaxf(m_i[r], tm);
      alpha[r] = __expf(m_i[r] - mn);
      m_i[r] = mn;
      float ps = 0.f;
#pragma unroll
      for (int nt = 0; nt < 4; ++nt) { p[nt][r] = __expf(sc[nt][r] - mn); ps += p[nt][r]; }
      ps += __shfl_xor(ps, 1, 64);
      ps += __shfl_xor(ps, 2, 64);
      ps += __shfl_xor(ps, 4, 64);
      ps += __shfl_xor(ps, 8, 64);
      l_i[r] = l_i[r] * alpha[r] + ps;
    }

#pragma unroll
    for (int nt = 0; nt < 4; ++nt)
#pragma unroll
      for (int r = 0; r < 4; ++r)
        Ps[(wid * 16 + rowg * 4 + r) * 72 + nt * 16 + cl] = f2b(p[nt][r]);
    __syncthreads();

#pragma unroll
    for (int nt = 0; nt < 4; ++nt)
#pragma unroll
      for (int r = 0; r < 4; ++r) O[nt][r] *= alpha[r];
    short8 aP[2];
#pragma unroll
    for (int ks = 0; ks < 2; ++ks)
      aP[ks] = *(const short8*)&Ps[(wid * 16 + cl) * 72 + ks * 32 + kq];
#pragma unroll
    for (int nt = 0; nt < 4; ++nt)
#pragma unroll
      for (int ks = 0; ks < 2; ++ks) {
        const short8 bV = *(const short8*)&Vt[(nt * 16 + cl) * 72 + ks * 32 + kq];
        O[nt] = __builtin_amdgcn_mfma_f32_16x16x32_bf16(aP[ks], bV, O[nt], 0, 0, 0);
      }
  }

#pragma unroll
  for (int nt = 0; nt < 4; ++nt) {
    const int d = nt * 16 + cl;
#pragma unroll
    for (int r = 0; r < 4; ++r) {
      const int i = q0 + wid * 16 + rowg * 4 + r;
      ctx[(rowb + i) * 1024 + h * 64 + d] = f2b(O[nt][r] / l_i[r]);
    }
  }
}

// ---------------------------------------------------------------------------
// Residual + LayerNorm (unchanged). In-place safe per-row.
// ---------------------------------------------------------------------------
template<int AF32, int BF32, int OF32>
__global__ __launch_bounds__(256) void ln_k(
    const void* __restrict__ a, const void* __restrict__ b,
    const float* __restrict__ g, const float* __restrict__ be,
    void* __restrict__ o)
{
  __shared__ float rbuf[8];
  const int tid = threadIdx.x;
  const size_t base = (size_t)blockIdx.x * 1024;
  const int lane = tid & 63, wid = tid >> 6;

  float xv[4], s = 0.f, sq = 0.f;
#pragma unroll
  for (int t = 0; t < 4; ++t) {
    const int c = tid + t * 256;
    const float av = AF32 ? ((const float*)a)[base + c]
                          : b2f(((const unsigned short*)a)[base + c]);
    const float bv = BF32 ? ((const float*)b)[base + c]
                          : b2f(((const unsigned short*)b)[base + c]);
    const float x = av + bv;
    xv[t] = x; s += x; sq += x * x;
  }
  for (int o2 = 1; o2 < 64; o2 <<= 1) { s += __shfl_xor(s, o2, 64); sq += __shfl_xor(sq, o2, 64); }
  if (lane == 0) { rbuf[wid] = s; rbuf[wid + 4] = sq; }
  __syncthreads();
  s  = rbuf[0] + rbuf[1] + rbuf[2] + rbuf[3];
  sq = rbuf[4] + rbuf[5] + rbuf[6] + rbuf[7];
  const float mean = s * (1.0f / 1024.f);
  const float var = sq * (1.0f / 1024.f) - mean * mean;
  const float rstd = rsqrtf(var + 1e-5f);
#pragma unroll
  for (int t = 0; t < 4; ++t) {
    const int c = tid + t * 256;
    const float y = (xv[t] - mean) * rstd * g[c] + be[c];
    if (OF32) ((float*)o)[base + c] = y;
    else      ((unsigned short*)o)[base + c] = f2b(y);
  }
}

// ---------------------------------------------------------------------------
extern "C" void kernel_launch(void* const* d_in, const int* in_sizes, int n_in,
                              void* d_out, int out_size, void* d_ws, size_t ws_size,
                              hipStream_t stream)
{
  (void)in_sizes; (void)n_in; (void)out_size; (void)ws_size;
  const float* src   = (const float*)d_in[0];
  const float* w_in  = (const float*)d_in[1];
  const float* b_in  = (const float*)d_in[2];
  const float* w_out = (const float*)d_in[3];
  const float* b_out = (const float*)d_in[4];
  const float* w1    = (const float*)d_in[5];
  const float* b1    = (const float*)d_in[6];
  const float* w2    = (const float*)d_in[7];
  const float* b2    = (const float*)d_in[8];
  const float* g1    = (const float*)d_in[9];
  const float* be1   = (const float*)d_in[10];
  const float* g2    = (const float*)d_in[11];
  const float* be2   = (const float*)d_in[12];

  char* ws = (char*)d_ws;
  unsigned short* srcb  = (unsigned short*)(ws);                 // [0, 8388608)
  unsigned short* x1b   = srcb;                                  // in-place over srcb
  unsigned short* qkv   = (unsigned short*)(ws + 8388608);       // [8388608, 33554432)
  unsigned short* ctx   = (unsigned short*)(ws + 33554432);      // [33554432, 41943040)
  unsigned short* attnb = (unsigned short*)(ws + 8388608);       // reuse qkv head
  unsigned short* ff1   = (unsigned short*)(ws + 8388608);       // [8388608, 41943040)
  unsigned short* wslot = (unsigned short*)(ws + 41943040);      // [41943040, 50331648)
  float*          outf  = (float*)d_out;

  // 0) fused convert: src -> srcb; w_in|w_out -> wslot (packed)
  conv3_k<<<dim3(4096), 256, 0, stream>>>(src, srcb, w_in, w_out, wslot);
  // 1) QKV projection (gemm256, grid 192) -> bf16 qkv
  gemm256<0, 0><<<dim3(12, 16), 512, 0, stream>>>(srcb, wslot, b_in, qkv, 4096, 3072, 1024);
  // 2) banded MFMA flash attention -> bf16 ctx
  attn_mfma<<<dim3(1024), 256, 0, stream>>>(qkv, ctx);
  // 3) output projection (gemm64 2-wave) -> bf16 attnb
  gemm64<0><<<dim3(8, 64), 128, 0, stream>>>(ctx, wslot + 3145728, b_out, attnb, 4096, 1024, 1024);
  // 4) LN1(srcb bf16 + attnb bf16) -> bf16 x1b (in-place over srcb)
  ln_k<0, 0, 0><<<dim3(4096), 256, 0, stream>>>(srcb, attnb, g1, be1, x1b);
  // 5) convert lin1_w; FF1 + ReLU (gemm256, grid 256 = 1/CU) -> bf16 ff1
  conv_k<<<dim3(2048), 256, 0, stream>>>(w1, wslot, 4194304);
  gemm256<1, 0><<<dim3(16, 16), 512, 0, stream>>>(x1b, wslot, b1, ff1, 4096, 4096, 1024);
  // 6) convert lin2_w; FF2 (gemm64 2-wave) -> f32 into d_out
  conv_k<<<dim3(2048), 256, 0, stream>>>(w2, wslot, 4194304);
  gemm64<1><<<dim3(8, 64), 128, 0, stream>>>(ff1, wslot, b2, outf, 4096, 1024, 4096);
  // 7) LN2(x1b bf16 + d_out f32) -> f32 d_out (in-place, per-row safe)
  ln_k<0, 1, 1><<<dim3(4096), 256, 0, stream>>>(x1b, outf, g2, be2, outf);
}

// Round 7
// 305.918 us; speedup vs baseline: 1.0776x; 1.0094x over previous
//
#include <hip/hip_runtime.h>
#include <cstdint>
#include <cstddef>

// ---------------------------------------------------------------------------
// RestrictedTransformerEncoderLayer on MI355X (gfx950)  — ROUND 17
// B=2, L=2048, E=1024, H=16, D=64, FF=4096, WIN=128.
// R17: every {stage,wait,barrier,read-all,MFMA-burst,barrier} variant
// (R10-R16) pinned at 680-690 TF = the documented 2-phase plateau. gemm256
// rewritten as the verified 8-phase template (4 phases/K-tile):
//   P0: ds_read B-half0(4)+A-half0(8); stage A1(tile s+1); lgkm(8); bar;
//       lgkm0; 16 MFMA (mt0-3 x nt0-1); bar.
//   P1: ds_read B-half1(4); stage A0(tile s+2->dead region); bar; lgkm0;
//       16 MFMA (mt0-3 x nt2-3); bar.
//   P2: ds_read A-half1(8); stage B0(s+2); bar; lgkm0; 16 MFMA
//       (mt4-7 x nt0-1); bar.
//   P3: stage B1(s+2); vmcnt(6) [steady; 0 at s=steps-2]; bar; 16 MFMA
//       (mt4-7 x nt2-3); bar.
// Stage order per tile [A0,B0,B1,A1] offset by 7 half-slots => every stage
// hits an LDS half whose reads retired >=1 barrier earlier (structural
// deadness); counted vmcnt once per K-tile keeps 3 half-tiles in flight
// across barriers. Wave rows: mt0-3 in A-half0 (wm*64+mt*16), mt4-7 in
// A-half1 (+128); B cols nt0-1 half0 (wn*32+nt*16), nt2-3 half1 (+128).
// gemm64 reverted to R12-exact (best measured FF2: ~49us).
// Workspace (peak 50.33 MB): srcb/x1b [0,8.4M); qkv [8.4M,33.6M);
// ctx [33.6M,41.9M); attnb=qkv head; ff1 [8.4M,41.9M); wslot [41.9M,50.3M).
// ---------------------------------------------------------------------------

typedef __attribute__((ext_vector_type(8))) short short8;   // 8 x bf16 MFMA frag
typedef __attribute__((ext_vector_type(4))) float f32x4;    // MFMA accumulator

__device__ __forceinline__ float b2f(unsigned short u) {
  union { unsigned int i; float f; } x; x.i = ((unsigned int)u) << 16; return x.f;
}
__device__ __forceinline__ unsigned short f2b(float f) {
  union { float f; unsigned int i; } x; x.f = f;
  unsigned int i = x.i;
  unsigned int r = (i + 0x7FFFu + ((i >> 16) & 1u)) >> 16;  // RNE
  return (unsigned short)r;
}
__device__ __forceinline__ uint4 pack8(float4 f0, float4 f1) {
  uint4 r;
  r.x = (unsigned)f2b(f0.x) | ((unsigned)f2b(f0.y) << 16);
  r.y = (unsigned)f2b(f0.z) | ((unsigned)f2b(f0.w) << 16);
  r.z = (unsigned)f2b(f1.x) | ((unsigned)f2b(f1.y) << 16);
  r.w = (unsigned)f2b(f1.z) | ((unsigned)f2b(f1.w) << 16);
  return r;
}

// async global->LDS, 16B/lane; LDS base wave-uniform, lanes write base+lane*16
__device__ __forceinline__ void gl_lds16(const unsigned short* g, unsigned short* l) {
  __builtin_amdgcn_global_load_lds(
      (const __attribute__((address_space(1))) unsigned int*)g,
      (__attribute__((address_space(3))) unsigned int*)l, 16, 0, 0);
}

// ---------------------------------------------------------------------------
// f32 -> bf16 convert (single array)
// ---------------------------------------------------------------------------
__global__ __launch_bounds__(256) void conv_k(
    const float* __restrict__ in, unsigned short* __restrict__ out, int n)
{
  const int i = (blockIdx.x * 256 + threadIdx.x) * 8;
  if (i < n) {
    const float4 f0 = *(const float4*)(in + i);
    const float4 f1 = *(const float4*)(in + i + 4);
    *(uint4*)(out + i) = pack8(f0, f1);
  }
}

// ---------------------------------------------------------------------------
// Fused convert: src (4194304) -> srcb; w_in (3145728) + w_out (1048576)
// -> wslot packed [w_in | w_out]. Total 8388608 elems, grid 4096 x 256.
// ---------------------------------------------------------------------------
__global__ __launch_bounds__(256) void conv3_k(
    const float* __restrict__ src, unsigned short* __restrict__ srcb,
    const float* __restrict__ w_in, const float* __restrict__ w_out,
    unsigned short* __restrict__ wslot)
{
  const int i = (blockIdx.x * 256 + threadIdx.x) * 8;
  const float* in;
  unsigned short* out;
  if (i < 4194304)      { in = src + i;                 out = srcb + i; }
  else if (i < 7340032) { in = w_in + (i - 4194304);    out = wslot + (i - 4194304); }
  else                  { in = w_out + (i - 7340032);   out = wslot + (i - 4194304); }
  const float4 f0 = *(const float4*)(in);
  const float4 f1 = *(const float4*)(in + 4);
  *(uint4*)(out) = pack8(f0, f1);
}

// ---------------------------------------------------------------------------
// GEMM 256x256 tile, BK=64, 8-phase schedule (4 phases per K-tile).
// 512 threads = 8 waves (2M x 4N); per-wave 128x64 split as half-rows.
// LDS 128 KB. r-rotation chunk swizzle (conflict-free).
// ---------------------------------------------------------------------------
template<int RELU, int OUT32>
__global__ __launch_bounds__(512, 2) void gemm256(
    const unsigned short* __restrict__ A, const unsigned short* __restrict__ Wb,
    const float* __restrict__ bias, void* __restrict__ out,
    int M, int N, int K)
{
  __shared__ unsigned short As[2][256 * 64];   // 64 KB
  __shared__ unsigned short Bs[2][256 * 64];   // 64 KB

  const int tid = threadIdx.x;
  const int lane = tid & 63, wid = tid >> 6;
  const int wm = wid >> 2, wn = wid & 3;       // wave grid 2M x 4N

  // XCD-aware bijective remap (grids 192 / 256, both % 8 == 0)
  const int gx = gridDim.x;
  const int flat = blockIdx.y * gx + blockIdx.x;
  const int chunk = (gx * gridDim.y) >> 3;
  const int nf = (flat & 7) * chunk + (flat >> 3);
  const int m0 = (nf / gx) * 256, n0 = (nf % gx) * 256;

  // staging precompute: half h1 in {0 (rows 0-127), 1 (rows 128-255)}, i in {0,1}
  int offA[2][2], offB[2][2], ldsO2[2][2];
#pragma unroll
  for (int h1 = 0; h1 < 2; ++h1)
#pragma unroll
    for (int i = 0; i < 2; ++i) {
      const int sl = i * 512 + tid;            // slot within half (0..1023)
      const int r = h1 * 128 + (sl >> 3);
      const int sslot = sl & 7;
      const int c = (sslot + r) & 7;
      offA[h1][i] = (m0 + r) * K + c * 8;
      offB[h1][i] = (n0 + r) * K + c * 8;
      ldsO2[h1][i] = (h1 * 1024 + i * 512 + (tid & ~63)) * 8;
    }

  const int cl = lane & 15;
  const int kg = lane >> 4;

  // reader offsets: rows mt0-3 at wm*64+mt*16 (half0); mt4-7 = +8192 bytes? (elems +8192)
  int aoff[4][2], boff[2][2];
#pragma unroll
  for (int mt = 0; mt < 4; ++mt) {
    const int ar = wm * 64 + mt * 16 + cl;
#pragma unroll
    for (int ks = 0; ks < 2; ++ks)
      aoff[mt][ks] = ar * 64 + (((ks * 4 + kg) - ar) & 7) * 8;
  }
#pragma unroll
  for (int nt = 0; nt < 2; ++nt) {
    const int br = wn * 32 + nt * 16 + cl;
#pragma unroll
    for (int ks = 0; ks < 2; ++ks)
      boff[nt][ks] = br * 64 + (((ks * 4 + kg) - br) & 7) * 8;
  }
  // rows +128: row*64 + ((k - row-128)&7)*8 = +8192 elems, rotation unchanged (128&7==0)

  f32x4 acc[8][4];
#pragma unroll
  for (int i = 0; i < 8; ++i)
#pragma unroll
    for (int j = 0; j < 4; ++j) acc[i][j] = (f32x4){0.f, 0.f, 0.f, 0.f};

  const int steps = K >> 6;

  // stage half-slot: global position idx; tile T=idx>>2 -> buf T&1;
  // j=idx&3 meaning [0]=A rows0-127, [1]=B rows0-127, [2]=B rows128-255, [3]=A rows128-255
#define STAGE256(idx_) do { const int _x = (idx_); if (_x < 4 * steps) {        \
    const int T_ = _x >> 2, j_ = _x & 3, bf_ = T_ & 1; const int ko = T_ << 6;  \
    if (j_ == 0)      { gl_lds16(A  + offA[0][0] + ko, &As[bf_][ldsO2[0][0]]);  \
                        gl_lds16(A  + offA[0][1] + ko, &As[bf_][ldsO2[0][1]]); }\
    else if (j_ == 1) { gl_lds16(Wb + offB[0][0] + ko, &Bs[bf_][ldsO2[0][0]]);  \
                        gl_lds16(Wb + offB[0][1] + ko, &Bs[bf_][ldsO2[0][1]]); }\
    else if (j_ == 2) { gl_lds16(Wb + offB[1][0] + ko, &Bs[bf_][ldsO2[1][0]]);  \
                        gl_lds16(Wb + offB[1][1] + ko, &Bs[bf_][ldsO2[1][1]]); }\
    else              { gl_lds16(A  + offA[1][0] + ko, &As[bf_][ldsO2[1][0]]);  \
                        gl_lds16(A  + offA[1][1] + ko, &As[bf_][ldsO2[1][1]]); }\
  } } while (0)

  // prologue: positions 0..6 = tile0 {A0,B0,B1,A1} + tile1 {A0,B0,B1}
  STAGE256(0); STAGE256(1); STAGE256(2); STAGE256(3);
  STAGE256(4); STAGE256(5); STAGE256(6);
  asm volatile("s_waitcnt vmcnt(6)" ::: "memory");   // tile0 fully landed
  __builtin_amdgcn_s_barrier();

  int cur = 0;
  for (int s = 0; s < steps; ++s) {
    // ---- P0: read B-half0 + A-half0; stage tile s+1's A1 (other buffer)
    short8 bf0[2][2], af[4][2];
#pragma unroll
    for (int nt = 0; nt < 2; ++nt)
#pragma unroll
      for (int ks = 0; ks < 2; ++ks) bf0[nt][ks] = *(const short8*)&Bs[cur][boff[nt][ks]];
#pragma unroll
    for (int mt = 0; mt < 4; ++mt)
#pragma unroll
      for (int ks = 0; ks < 2; ++ks) af[mt][ks] = *(const short8*)&As[cur][aoff[mt][ks]];
    STAGE256(4 * s + 7);
    asm volatile("s_waitcnt lgkmcnt(8)" ::: "memory");
    __builtin_amdgcn_s_barrier();
    asm volatile("s_waitcnt lgkmcnt(0)" ::: "memory");
    __builtin_amdgcn_sched_barrier(0);
    __builtin_amdgcn_s_setprio(1);
#pragma unroll
    for (int mt = 0; mt < 4; ++mt)
#pragma unroll
      for (int nt = 0; nt < 2; ++nt)
#pragma unroll
        for (int ks = 0; ks < 2; ++ks)
          acc[mt][nt] = __builtin_amdgcn_mfma_f32_16x16x32_bf16(af[mt][ks], bf0[nt][ks], acc[mt][nt], 0, 0, 0);
    __builtin_amdgcn_s_setprio(0);
    __builtin_amdgcn_s_barrier();

    // ---- P1: read B-half1; stage tile s+2's A0 (dead since P0)
    short8 bf1[2][2];
#pragma unroll
    for (int nt = 0; nt < 2; ++nt)
#pragma unroll
      for (int ks = 0; ks < 2; ++ks) bf1[nt][ks] = *(const short8*)&Bs[cur][boff[nt][ks] + 8192];
    STAGE256(4 * s + 8);
    __builtin_amdgcn_s_barrier();
    asm volatile("s_waitcnt lgkmcnt(0)" ::: "memory");
    __builtin_amdgcn_sched_barrier(0);
    __builtin_amdgcn_s_setprio(1);
#pragma unroll
    for (int mt = 0; mt < 4; ++mt)
#pragma unroll
      for (int nt = 0; nt < 2; ++nt)
#pragma unroll
        for (int ks = 0; ks < 2; ++ks)
          acc[mt][nt + 2] = __builtin_amdgcn_mfma_f32_16x16x32_bf16(af[mt][ks], bf1[nt][ks], acc[mt][nt + 2], 0, 0, 0);
    __builtin_amdgcn_s_setprio(0);
    __builtin_amdgcn_s_barrier();

    // ---- P2: read A-half1; stage tile s+2's B0 (dead since P0)
    short8 ag[4][2];
#pragma unroll
    for (int mt = 0; mt < 4; ++mt)
#pragma unroll
      for (int ks = 0; ks < 2; ++ks) ag[mt][ks] = *(const short8*)&As[cur][aoff[mt][ks] + 8192];
    STAGE256(4 * s + 9);
    __builtin_amdgcn_s_barrier();
    asm volatile("s_waitcnt lgkmcnt(0)" ::: "memory");
    __builtin_amdgcn_sched_barrier(0);
    __builtin_amdgcn_s_setprio(1);
#pragma unroll
    for (int mt = 0; mt < 4; ++mt)
#pragma unroll
      for (int nt = 0; nt < 2; ++nt)
#pragma unroll
        for (int ks = 0; ks < 2; ++ks)
          acc[mt + 4][nt] = __builtin_amdgcn_mfma_f32_16x16x32_bf16(ag[mt][ks], bf0[nt][ks], acc[mt + 4][nt], 0, 0, 0);
    __builtin_amdgcn_s_setprio(0);
    __builtin_amdgcn_s_barrier();

    // ---- P3: stage tile s+2's B1 (dead since P1); counted vmcnt; MFMA
    STAGE256(4 * s + 10);
    if (s < steps - 2)       asm volatile("s_waitcnt vmcnt(6)" ::: "memory");
    else if (s == steps - 2) asm volatile("s_waitcnt vmcnt(0)" ::: "memory");
    __builtin_amdgcn_s_barrier();   // tile s+1 now fully visible
    __builtin_amdgcn_s_setprio(1);
#pragma unroll
    for (int mt = 0; mt < 4; ++mt)
#pragma unroll
      for (int nt = 0; nt < 2; ++nt)
#pragma unroll
        for (int ks = 0; ks < 2; ++ks)
          acc[mt + 4][nt + 2] = __builtin_amdgcn_mfma_f32_16x16x32_bf16(ag[mt][ks], bf1[nt][ks], acc[mt + 4][nt + 2], 0, 0, 0);
    __builtin_amdgcn_s_setprio(0);
    __builtin_amdgcn_s_barrier();

    cur ^= 1;
  }
#undef STAGE256

  // epilogue: C/D mapping col = cl, row = kg*4 + r  [m89-verified]
#pragma unroll
  for (int nt = 0; nt < 4; ++nt) {
    const int colB = wn * 32 + (nt & 1) * 16 + (nt >> 1) * 128;
    const int col = n0 + colB + cl;
    const float bvs = bias[col];
#pragma unroll
    for (int mt = 0; mt < 8; ++mt) {
      const int rowA = wm * 64 + (mt & 3) * 16 + (mt >> 2) * 128;
#pragma unroll
      for (int r = 0; r < 4; ++r) {
        const int grow = m0 + rowA + kg * 4 + r;
        float v = acc[mt][nt][r] + bvs;
        if (RELU) v = fmaxf(v, 0.f);
        if (OUT32) ((float*)out)[(size_t)grow * N + col] = v;
        else       ((unsigned short*)out)[(size_t)grow * N + col] = f2b(v);
      }
    }
  }
}

// ---------------------------------------------------------------------------
// GEMM 64x128 tile, BK=64 — N=1024 shapes (grid 512 = 2 blocks/CU).
// R12-exact: 3-deep counted-vmcnt pipeline (72 KB LDS), 4 waves, no
// ks-split, no setprio (both measured regressions). XCD-chunked remap.
// ---------------------------------------------------------------------------
template<int OUT32>
__global__ __launch_bounds__(256) void gemm64(
    const unsigned short* __restrict__ A, const unsigned short* __restrict__ Wb,
    const float* __restrict__ bias, void* __restrict__ out,
    int M, int N, int K)
{
  __shared__ unsigned short As[3][64 * 64];    // 24 KB
  __shared__ unsigned short Bs[3][128 * 64];   // 48 KB

  const int tid = threadIdx.x;
  const int lane = tid & 63, wid = tid >> 6;

  const int nwgx = gridDim.x;
  const int flat = blockIdx.y * nwgx + blockIdx.x;
  const int chunk = (nwgx * gridDim.y) >> 3;
  const int nf = (flat & 7) * chunk + (flat >> 3);
  const int m0 = (nf / nwgx) * 64, n0 = (nf % nwgx) * 128;

  const unsigned short* gA[2];
  const unsigned short* gW[4];
  int ldsA[2], ldsB[4];
#pragma unroll
  for (int i = 0; i < 2; ++i) {
    const int sl = wid * 128 + i * 64 + lane;
    const int r = sl >> 3, s = sl & 7, c = (s + r) & 7;
    gA[i] = A + (size_t)(m0 + r) * K + c * 8;
    ldsA[i] = (wid * 128 + i * 64) * 8;
  }
#pragma unroll
  for (int i = 0; i < 4; ++i) {
    const int sl = wid * 256 + i * 64 + lane;
    const int r = sl >> 3, s = sl & 7, c = (s + r) & 7;
    gW[i] = Wb + (size_t)(n0 + r) * K + c * 8;
    ldsB[i] = (wid * 256 + i * 64) * 8;
  }

  const int cl = lane & 15;
  const int kg = lane >> 4;
  int aoff[4][2], boff[2][2];
#pragma unroll
  for (int t = 0; t < 4; ++t) {
    const int ar = t * 16 + cl;
#pragma unroll
    for (int ks = 0; ks < 2; ++ks)
      aoff[t][ks] = ar * 64 + ((ks * 4 + kg - ar) & 7) * 8;
  }
#pragma unroll
  for (int t = 0; t < 2; ++t) {
    const int br = wid * 32 + t * 16 + cl;
#pragma unroll
    for (int ks = 0; ks < 2; ++ks)
      boff[t][ks] = br * 64 + ((ks * 4 + kg - br) & 7) * 8;
  }

  f32x4 acc[4][2];
#pragma unroll
  for (int i = 0; i < 4; ++i)
#pragma unroll
    for (int j = 0; j < 2; ++j) acc[i][j] = (f32x4){0.f, 0.f, 0.f, 0.f};

  const int steps = K >> 6;

  const int pre = steps < 3 ? steps : 3;
  for (int t = 0; t < pre; ++t) {
#pragma unroll
    for (int i = 0; i < 2; ++i) { gl_lds16(gA[i], &As[t][ldsA[i]]); gA[i] += 64; }
#pragma unroll
    for (int i = 0; i < 4; ++i) { gl_lds16(gW[i], &Bs[t][ldsB[i]]); gW[i] += 64; }
  }

  int cur = 0;
  for (int s = 0; s < steps; ++s) {
    const int rem = steps - 1 - s;
    if (rem >= 2)      asm volatile("s_waitcnt vmcnt(12)" ::: "memory");
    else if (rem == 1) asm volatile("s_waitcnt vmcnt(6)" ::: "memory");
    else               asm volatile("s_waitcnt vmcnt(0)" ::: "memory");
    __builtin_amdgcn_s_barrier();

    short8 af[4][2], bf[2][2];
#pragma unroll
    for (int t = 0; t < 4; ++t)
#pragma unroll
      for (int ks = 0; ks < 2; ++ks) af[t][ks] = *(const short8*)&As[cur][aoff[t][ks]];
#pragma unroll
    for (int t = 0; t < 2; ++t)
#pragma unroll
      for (int ks = 0; ks < 2; ++ks) bf[t][ks] = *(const short8*)&Bs[cur][boff[t][ks]];

    asm volatile("s_waitcnt lgkmcnt(0)" ::: "memory");
    __builtin_amdgcn_sched_barrier(0);
    __builtin_amdgcn_s_barrier();

    if (s + 3 < steps) {
#pragma unroll
      for (int i = 0; i < 2; ++i) { gl_lds16(gA[i], &As[cur][ldsA[i]]); gA[i] += 64; }
#pragma unroll
      for (int i = 0; i < 4; ++i) { gl_lds16(gW[i], &Bs[cur][ldsB[i]]); gW[i] += 64; }
    }

#pragma unroll
    for (int mt = 0; mt < 4; ++mt)
#pragma unroll
      for (int nt = 0; nt < 2; ++nt)
#pragma unroll
        for (int ks = 0; ks < 2; ++ks)
          acc[mt][nt] = __builtin_amdgcn_mfma_f32_16x16x32_bf16(af[mt][ks], bf[nt][ks], acc[mt][nt], 0, 0, 0);

    cur = (cur == 2) ? 0 : cur + 1;
  }

#pragma unroll
  for (int nt = 0; nt < 2; ++nt) {
    const int col = n0 + wid * 32 + nt * 16 + cl;
    const float bvs = bias[col];
#pragma unroll
    for (int mt = 0; mt < 4; ++mt) {
#pragma unroll
      for (int r = 0; r < 4; ++r) {
        const int grow = m0 + mt * 16 + kg * 4 + r;
        const float v = acc[mt][nt][r] + bvs;
        if (OUT32) ((float*)out)[(size_t)grow * N + col] = v;
        else       ((unsigned short*)out)[(size_t)grow * N + col] = f2b(v);
      }
    }
  }
}

// ---------------------------------------------------------------------------
// MFMA flash attention (unchanged from passing r6-r9).
// ---------------------------------------------------------------------------
__global__ __launch_bounds__(256) void attn_mfma(
    const unsigned short* __restrict__ qkv, unsigned short* __restrict__ ctx)
{
  __shared__ unsigned short Ks[64 * 72];
  __shared__ unsigned short Vt[64 * 72];
  __shared__ unsigned short Ps[64 * 72];

  const int tid = threadIdx.x;
  const int bid = blockIdx.x;
  const int qt = bid & 31, h = (bid >> 5) & 15, b = bid >> 9;
  const int q0 = qt * 64;
  const int wstart = max(0, q0 - 128);
  const int wend = min(2048, q0 + 64 + 128);
  const int ntile = (wend - wstart + 63) >> 6;
  const size_t rowb = (size_t)b * 2048;

  const int lane = tid & 63, wid = tid >> 6;
  const int cl = lane & 15;
  const int kq = (lane >> 4) * 8;
  const int rowg = lane >> 4;

  short8 aQ[2];
#pragma unroll
  for (int ks = 0; ks < 2; ++ks)
    aQ[ks] = *(const short8*)(qkv + (rowb + q0 + wid * 16 + cl) * 3072 + h * 64 + ks * 32 + kq);

  float m_i[4], l_i[4];
  f32x4 O[4];
#pragma unroll
  for (int r = 0; r < 4; ++r) { m_i[r] = -1.0e30f; l_i[r] = 0.f; }
#pragma unroll
  for (int nt = 0; nt < 4; ++nt) O[nt] = (f32x4){0.f, 0.f, 0.f, 0.f};

  for (int t = 0; t < ntile; ++t) {
    const int jbase = wstart + t * 64;
    __syncthreads();
    for (int idx = tid; idx < 512; idx += 256) {
      const int r = idx >> 3, c = idx & 7;
      const int jg = jbase + r;
      uint4 kv = {0u, 0u, 0u, 0u}, vv = {0u, 0u, 0u, 0u};
      if (jg < wend) {
        const size_t base = (rowb + jg) * 3072 + h * 64 + c * 8;
        kv = *(const uint4*)(qkv + base + 1024);
        vv = *(const uint4*)(qkv + base + 2048);
      }
      *(uint4*)&Ks[r * 72 + c * 8] = kv;
      const unsigned short* vs = (const unsigned short*)&vv;
#pragma unroll
      for (int ii = 0; ii < 8; ++ii) Vt[(c * 8 + ii) * 72 + r] = vs[ii];
    }
    __syncthreads();

    f32x4 S[4];
#pragma unroll
    for (int nt = 0; nt < 4; ++nt) S[nt] = (f32x4){0.f, 0.f, 0.f, 0.f};
#pragma unroll
    for (int nt = 0; nt < 4; ++nt)
#pragma unroll
      for (int ks = 0; ks < 2; ++ks) {
        const short8 bK = *(const short8*)&Ks[(nt * 16 + cl) * 72 + ks * 32 + kq];
        S[nt] = __builtin_amdgcn_mfma_f32_16x16x32_bf16(aQ[ks], bK, S[nt], 0, 0, 0);
      }

    float sc[4][4];
#pragma unroll
    for (int nt = 0; nt < 4; ++nt) {
      const int jg = jbase + nt * 16 + cl;
#pragma unroll
      for (int r = 0; r < 4; ++r) {
        const int i = q0 + wid * 16 + rowg * 4 + r;
        const bool v = (jg < wend) && (jg >= i - 128) && (jg <= i + 128);
        sc[nt][r] = v ? S[nt][r] * 0.125f : -1.0e30f;
      }
    }

    float alpha[4], p[4][4];
#pragma unroll
    for (int r = 0; r < 4; ++r) {
      float tm = fmaxf(fmaxf(sc[0][r], sc[1][r]), fmaxf(sc[2][r], sc[3][r]));
      tm = fmaxf(tm, __shfl_xor(tm, 1, 64));
      tm = fmaxf(tm, __shfl_xor(tm, 2, 64));
      tm = fmaxf(tm, __shfl_xor(tm, 4, 64));
      tm = fmaxf(tm, __shfl_xor(tm, 8, 64));
      const float mn = fmaxf(m_i[r], tm);
      alpha[r] = __expf(m_i[r] - mn);
      m_i[r] = mn;
      float ps = 0.f;
#pragma unroll
      for (int nt = 0; nt < 4; ++nt) { p[nt][r] = __expf(sc[nt][r] - mn); ps += p[nt][r]; }
      ps += __shfl_xor(ps, 1, 64);
      ps += __shfl_xor(ps, 2, 64);
      ps += __shfl_xor(ps, 4, 64);
      ps += __shfl_xor(ps, 8, 64);
      l_i[r] = l_i[r] * alpha[r] + ps;
    }

#pragma unroll
    for (int nt = 0; nt < 4; ++nt)
#pragma unroll
      for (int r = 0; r < 4; ++r)
        Ps[(wid * 16 + rowg * 4 + r) * 72 + nt * 16 + cl] = f2b(p[nt][r]);
    __syncthreads();

#pragma unroll
    for (int nt = 0; nt < 4; ++nt)
#pragma unroll
      for (int r = 0; r < 4; ++r) O[nt][r] *= alpha[r];
    short8 aP[2];
#pragma unroll
    for (int ks = 0; ks < 2; ++ks)
      aP[ks] = *(const short8*)&Ps[(wid * 16 + cl) * 72 + ks * 32 + kq];
#pragma unroll
    for (int nt = 0; nt < 4; ++nt)
#pragma unroll
      for (int ks = 0; ks < 2; ++ks) {
        const short8 bV = *(const short8*)&Vt[(nt * 16 + cl) * 72 + ks * 32 + kq];
        O[nt] = __builtin_amdgcn_mfma_f32_16x16x32_bf16(aP[ks], bV, O[nt], 0, 0, 0);
      }
  }

#pragma unroll
  for (int nt = 0; nt < 4; ++nt) {
    const int d = nt * 16 + cl;
#pragma unroll
    for (int r = 0; r < 4; ++r) {
      const int i = q0 + wid * 16 + rowg * 4 + r;
      ctx[(rowb + i) * 1024 + h * 64 + d] = f2b(O[nt][r] / l_i[r]);
    }
  }
}

// ---------------------------------------------------------------------------
// Residual + LayerNorm (unchanged). In-place safe per-row.
// ---------------------------------------------------------------------------
template<int AF32, int BF32, int OF32>
__global__ __launch_bounds__(256) void ln_k(
    const void* __restrict__ a, const void* __restrict__ b,
    const float* __restrict__ g, const float* __restrict__ be,
    void* __restrict__ o)
{
  __shared__ float rbuf[8];
  const int tid = threadIdx.x;
  const size_t base = (size_t)blockIdx.x * 1024;
  const int lane = tid & 63, wid = tid >> 6;

  float xv[4], s = 0.f, sq = 0.f;
#pragma unroll
  for (int t = 0; t < 4; ++t) {
    const int c = tid + t * 256;
    const float av = AF32 ? ((const float*)a)[base + c]
                          : b2f(((const unsigned short*)a)[base + c]);
    const float bv = BF32 ? ((const float*)b)[base + c]
                          : b2f(((const unsigned short*)b)[base + c]);
    const float x = av + bv;
    xv[t] = x; s += x; sq += x * x;
  }
  for (int o2 = 1; o2 < 64; o2 <<= 1) { s += __shfl_xor(s, o2, 64); sq += __shfl_xor(sq, o2, 64); }
  if (lane == 0) { rbuf[wid] = s; rbuf[wid + 4] = sq; }
  __syncthreads();
  s  = rbuf[0] + rbuf[1] + rbuf[2] + rbuf[3];
  sq = rbuf[4] + rbuf[5] + rbuf[6] + rbuf[7];
  const float mean = s * (1.0f / 1024.f);
  const float var = sq * (1.0f / 1024.f) - mean * mean;
  const float rstd = rsqrtf(var + 1e-5f);
#pragma unroll
  for (int t = 0; t < 4; ++t) {
    const int c = tid + t * 256;
    const float y = (xv[t] - mean) * rstd * g[c] + be[c];
    if (OF32) ((float*)o)[base + c] = y;
    else      ((unsigned short*)o)[base + c] = f2b(y);
  }
}

// ---------------------------------------------------------------------------
extern "C" void kernel_launch(void* const* d_in, const int* in_sizes, int n_in,
                              void* d_out, int out_size, void* d_ws, size_t ws_size,
                              hipStream_t stream)
{
  (void)in_sizes; (void)n_in; (void)out_size; (void)ws_size;
  const float* src   = (const float*)d_in[0];
  const float* w_in  = (const float*)d_in[1];
  const float* b_in  = (const float*)d_in[2];
  const float* w_out = (const float*)d_in[3];
  const float* b_out = (const float*)d_in[4];
  const float* w1    = (const float*)d_in[5];
  const float* b1    = (const float*)d_in[6];
  const float* w2    = (const float*)d_in[7];
  const float* b2    = (const float*)d_in[8];
  const float* g1    = (const float*)d_in[9];
  const float* be1   = (const float*)d_in[10];
  const float* g2    = (const float*)d_in[11];
  const float* be2   = (const float*)d_in[12];

  char* ws = (char*)d_ws;
  unsigned short* srcb  = (unsigned short*)(ws);                 // [0, 8388608)
  unsigned short* x1b   = srcb;                                  // in-place over srcb
  unsigned short* qkv   = (unsigned short*)(ws + 8388608);       // [8388608, 33554432)
  unsigned short* ctx   = (unsigned short*)(ws + 33554432);      // [33554432, 41943040)
  unsigned short* attnb = (unsigned short*)(ws + 8388608);       // reuse qkv head
  unsigned short* ff1   = (unsigned short*)(ws + 8388608);       // [8388608, 41943040)
  unsigned short* wslot = (unsigned short*)(ws + 41943040);      // [41943040, 50331648)
  float*          outf  = (float*)d_out;

  // 0) fused convert: src -> srcb; w_in|w_out -> wslot (packed)
  conv3_k<<<dim3(4096), 256, 0, stream>>>(src, srcb, w_in, w_out, wslot);
  // 1) QKV projection (gemm256 8-phase, grid 192) -> bf16 qkv
  gemm256<0, 0><<<dim3(12, 16), 512, 0, stream>>>(srcb, wslot, b_in, qkv, 4096, 3072, 1024);
  // 2) banded MFMA flash attention -> bf16 ctx
  attn_mfma<<<dim3(1024), 256, 0, stream>>>(qkv, ctx);
  // 3) output projection (gemm64 R12) -> bf16 attnb
  gemm64<0><<<dim3(8, 64), 256, 0, stream>>>(ctx, wslot + 3145728, b_out, attnb, 4096, 1024, 1024);
  // 4) LN1(srcb bf16 + attnb bf16) -> bf16 x1b (in-place over srcb)
  ln_k<0, 0, 0><<<dim3(4096), 256, 0, stream>>>(srcb, attnb, g1, be1, x1b);
  // 5) convert lin1_w; FF1 + ReLU (gemm256 8-phase, grid 256) -> bf16 ff1
  conv_k<<<dim3(2048), 256, 0, stream>>>(w1, wslot, 4194304);
  gemm256<1, 0><<<dim3(16, 16), 512, 0, stream>>>(x1b, wslot, b1, ff1, 4096, 4096, 1024);
  // 6) convert lin2_w; FF2 (gemm64 R12) -> f32 into d_out
  conv_k<<<dim3(2048), 256, 0, stream>>>(w2, wslot, 4194304);
  gemm64<1><<<dim3(8, 64), 256, 0, stream>>>(ff1, wslot, b2, outf, 4096, 1024, 4096);
  // 7) LN2(x1b bf16 + d_out f32) -> f32 d_out (in-place, per-row safe)
  ln_k<0, 1, 1><<<dim3(4096), 256, 0, stream>>>(x1b, outf, g2, be2, outf);
}